// Round 7
// baseline (2290.732 us; speedup 1.0000x reference)
//
#include <hip/hip_runtime.h>

#define N_NODES 50000
#define N_EDGES 800000
#define F 64
#define EDIM 16
#define NPB 64                              // dst nodes per block
#define NBLK ((N_NODES + NPB - 1) / NPB)    // 782
#define TPB 256                             // 4 waves
#define NWAVE 4
#define NPW (NPB / NWAVE)                   // 16 nodes per wave (node phase)
#define EG 256                              // edges staged per group
#define NEG_SLOPE 0.01f
#define SCAN_B 1024
#define SCAN_NB ((N_NODES + SCAN_B - 1) / SCAN_B)   // 49

// ---------------- CSR build ----------------
__global__ __launch_bounds__(256) void hist_kernel(const int* __restrict__ ei,
                                                   int* __restrict__ count) {
    for (int e = blockIdx.x * blockDim.x + threadIdx.x; e < N_EDGES;
         e += gridDim.x * blockDim.x)
        atomicAdd(&count[ei[N_EDGES + e]], 1);
}

__global__ __launch_bounds__(SCAN_B) void scan_partial_kernel(const int* __restrict__ count,
                                                              int* __restrict__ rowptr,
                                                              int* __restrict__ blockSum) {
    __shared__ int buf[SCAN_B];
    const int b = blockIdx.x, tid = threadIdx.x;
    const int i = b * SCAN_B + tid;
    int v = (i < N_NODES) ? count[i] : 0;
    buf[tid] = v;
    __syncthreads();
    for (int off = 1; off < SCAN_B; off <<= 1) {
        int t = (tid >= off) ? buf[tid - off] : 0;
        __syncthreads();
        buf[tid] += t;
        __syncthreads();
    }
    if (i < N_NODES) rowptr[i] = buf[tid] - v;      // exclusive within block
    if (tid == SCAN_B - 1) blockSum[b] = buf[tid];
}

__global__ void scan_tops_kernel(int* __restrict__ blockSum, int* __restrict__ rowptrN) {
    const int lane = threadIdx.x;                    // 64 threads = 1 wave
    int v = (lane < SCAN_NB) ? blockSum[lane] : 0;
    int s = v;
    for (int off = 1; off < 64; off <<= 1) {
        int t = __shfl_up(s, off);
        if (lane >= off) s += t;
    }
    if (lane < SCAN_NB) blockSum[lane] = s - v;      // exclusive block offsets
    if (lane == 63) rowptrN[0] = s;                  // total -> rowptr[N_NODES]
}

__global__ __launch_bounds__(SCAN_B) void scan_add_kernel(const int* __restrict__ blockSum,
                                                          int* __restrict__ rowptr,
                                                          int* __restrict__ cursor) {
    const int i = blockIdx.x * SCAN_B + threadIdx.x;
    if (i < N_NODES) {
        int r = rowptr[i] + blockSum[blockIdx.x];
        rowptr[i] = r;
        cursor[i] = r;
    }
}

__global__ __launch_bounds__(256) void scatter_kernel(const int* __restrict__ ei,
                                                      int* __restrict__ cursor,
                                                      int2* __restrict__ pairsSD,
                                                      int* __restrict__ eid) {
    for (int e = blockIdx.x * blockDim.x + threadIdx.x; e < N_EDGES;
         e += gridDim.x * blockDim.x) {
        int s = ei[e];
        int d = ei[N_EDGES + e];
        int pos = atomicAdd(&cursor[d], 1);
        pairsSD[pos] = make_int2(s, d);
        eid[pos] = e;
    }
}

__global__ __launch_bounds__(256) void permute_kernel(const float4* __restrict__ ea4,
                                                      const int* __restrict__ eid,
                                                      float4* __restrict__ eaP) {
    int t = blockIdx.x * blockDim.x + threadIdx.x;
    if (t < N_EDGES * 4) {
        int j = t >> 2, c = t & 3;
        eaP[t] = ea4[((size_t)eid[j] << 2) + c];
    }
}

// ---------------- fuse readout weights ----------------
__global__ void fuse_weights_kernel(
    const float* __restrict__ W1, const float* __restrict__ b1,
    const float* __restrict__ W2, const float* __restrict__ b2,
    float* __restrict__ Wf, float* __restrict__ bf) {
    const int t = threadIdx.x;     // 128 threads
    const int i = t >> 1;
    const int j = t & 1;
    float acc = 0.f;
    for (int k = 0; k < 128; ++k) acc += W1[i * 128 + k] * W2[k * 2 + j];
    Wf[i * 2 + j] = acc;
    if (i == 0) {
        float accb = b2[j];
        for (int k = 0; k < 128; ++k) accb += b1[k] * W2[k * 2 + j];
        bf[j] = accb;
    }
}

// ---------------- fused GINE layer: LDS-staged ea, lane-per-edge chunks ----------------
template <bool LAST>
__global__ __launch_bounds__(TPB) void conv_kernel(
    const float* __restrict__ h,
    const int* __restrict__ rowptr,
    const int2* __restrict__ pairsSD,
    const int* __restrict__ eid,
    const float* __restrict__ eaSrc, const int usePerm,
    const float* __restrict__ We, const float* __restrict__ be,
    const float* __restrict__ Wn, const float* __restrict__ bn,
    const float* __restrict__ Wf, const float* __restrict__ bf,
    float* __restrict__ hout, float* __restrict__ out)
{
    __shared__ float aggrS[NPB * F];   // 16 KB, chunk-slot XOR-swizzled per node
    __shared__ float eaT[EDIM * EG];   // 16 KB, transposed: eaT[k][e]
    __shared__ int2  sdS[EG];          // 2 KB
    __shared__ float WeS[EDIM * F];    // 4 KB
    const int tid  = threadIdx.x;
    const int lane = tid & 63;
    const int wid  = tid >> 6;
    const int n0   = blockIdx.x * NPB;
    const int nCnt = min(NPB, N_NODES - n0);

    for (int i = tid; i < NPB * F; i += TPB) aggrS[i] = 0.f;
    for (int i = tid; i < EDIM * F; i += TPB) WeS[i] = We[i];
    __syncthreads();

    const int eBeg = rowptr[n0];
    const int eEnd = rowptr[n0 + nCnt];

    for (int base = eBeg; base < eEnd; base += EG) {
        const int cnt = min(EG, eEnd - base);
        // ---- stage ea (transposed) + pairs for this group; coalesced reads ----
        for (int t = tid; t < cnt * 4; t += TPB) {
            const int e = t >> 2, k4 = t & 3;
            const size_t row = usePerm ? (size_t)(base + e) : (size_t)eid[base + e];
            const float4 v = *((const float4*)eaSrc + (row << 2) + k4);
            eaT[(4 * k4 + 0) * EG + e] = v.x;
            eaT[(4 * k4 + 1) * EG + e] = v.y;
            eaT[(4 * k4 + 2) * EG + e] = v.z;
            eaT[(4 * k4 + 3) * EG + e] = v.w;
        }
        for (int t = tid; t < cnt; t += TPB) sdS[t] = pairsSD[base + t];
        __syncthreads();

        // ---- compute: wave w handles chunks {ci*4+w}; lane = edge ----
#pragma unroll 1
        for (int ci = 0; ci < 4; ++ci) {
            const int c = ci * NWAVE + wid;              // 0..15
            const float4 be4 = *(const float4*)&be[c * 4];
            float4 wq[EDIM];
#pragma unroll
            for (int k = 0; k < EDIM; ++k) wq[k] = *(const float4*)&WeS[k * F + c * 4];
#pragma unroll 2
            for (int r = 0; r < EG / 64; ++r) {
                const int e = (r << 6) + lane;
                if (e < cnt) {
                    const int2 sd = sdS[e];
                    const float4 h4 = *(const float4*)&h[((size_t)sd.x << 6) + c * 4];
                    float4 p = be4;
#pragma unroll
                    for (int k = 0; k < EDIM; ++k) {
                        const float a = eaT[k * EG + e];
                        p.x = fmaf(a, wq[k].x, p.x);
                        p.y = fmaf(a, wq[k].y, p.y);
                        p.z = fmaf(a, wq[k].z, p.z);
                        p.w = fmaf(a, wq[k].w, p.w);
                    }
                    const int nl = sd.y - n0;
                    const int slot = c ^ (nl & 15);
                    atomicAdd(&aggrS[(nl << 6) + (slot << 2) + 0], fmaxf(h4.x + p.x, 0.f));
                    atomicAdd(&aggrS[(nl << 6) + (slot << 2) + 1], fmaxf(h4.y + p.y, 0.f));
                    atomicAdd(&aggrS[(nl << 6) + (slot << 2) + 2], fmaxf(h4.z + p.z, 0.f));
                    atomicAdd(&aggrS[(nl << 6) + (slot << 2) + 3], fmaxf(h4.w + p.w, 0.f));
                }
            }
        }
        __syncthreads();
    }

    // ---- t = h + aggr (swizzle-aware, conflict-free) ----
    {
        const int cl_ = lane >> 2, il = lane & 3;
        for (int nl = wid; nl < nCnt; nl += NWAVE) {
            const int slot = cl_ ^ (nl & 15);
            aggrS[(nl << 6) + (slot << 2) + il] += h[((size_t)(n0 + nl) << 6) + lane];
        }
    }
    __syncthreads();

    // ---- node GEMM: 16 nodes/wave; Wn coalesced loads; t via uniform b128 broadcasts ----
    const int nlBase = wid * NPW;   // multiple of 16 -> (nlBase+i)&15 == i
    float accv[NPW];
    const float bnR = bn[lane];
#pragma unroll
    for (int i = 0; i < NPW; ++i) accv[i] = bnR;
#pragma unroll
    for (int q = 0; q < 16; ++q) {
        const float w0 = Wn[(4 * q + 0) * F + lane];
        const float w1 = Wn[(4 * q + 1) * F + lane];
        const float w2 = Wn[(4 * q + 2) * F + lane];
        const float w3 = Wn[(4 * q + 3) * F + lane];
#pragma unroll
        for (int i = 0; i < NPW; ++i) {
            const int slot = q ^ i;
            const float4 t4 = *(const float4*)&aggrS[((nlBase + i) << 6) + (slot << 2)];
            accv[i] = fmaf(t4.w, w3, fmaf(t4.z, w2, fmaf(t4.y, w1, fmaf(t4.x, w0, accv[i]))));
        }
    }
    float wf0 = 0.f, wf1 = 0.f, bf0 = 0.f, bf1 = 0.f;
    if (LAST) { wf0 = Wf[lane * 2]; wf1 = Wf[lane * 2 + 1]; bf0 = bf[0]; bf1 = bf[1]; }
#pragma unroll
    for (int i = 0; i < NPW; ++i) {
        const int nl = nlBase + i;
        if (nl >= nCnt) break;
        float acc = accv[i];
        acc = acc >= 0.f ? acc : NEG_SLOPE * acc;            // LeakyReLU
        if (!LAST) {
            hout[((size_t)(n0 + nl) << 6) + lane] = acc;
        } else {
            float v0 = acc * wf0, v1 = acc * wf1;
#pragma unroll
            for (int off = 32; off; off >>= 1) {
                v0 += __shfl_down(v0, off);
                v1 += __shfl_down(v1, off);
            }
            if (lane == 0) {
                out[(n0 + nl) * 2 + 0] = v0 + bf0;
                out[(n0 + nl) * 2 + 1] = v1 + bf1;
            }
        }
    }
}

extern "C" void kernel_launch(void* const* d_in, const int* in_sizes, int n_in,
                              void* d_out, int out_size, void* d_ws, size_t ws_size,
                              hipStream_t stream) {
    const float* x  = (const float*)d_in[0];
    const int*   ei = (const int*)d_in[1];
    const float* ea = (const float*)d_in[2];
    const float* Wn = (const float*)d_in[3];
    const float* bn = (const float*)d_in[4];
    const float* We = (const float*)d_in[5];     // [3,16,64]
    const float* be = (const float*)d_in[6];     // [3,64]
    const float* W1 = (const float*)d_in[7];
    const float* b1 = (const float*)d_in[8];
    const float* W2 = (const float*)d_in[9];
    const float* b2 = (const float*)d_in[10];
    float* out = (float*)d_out;

    size_t off = 0;
    char* base = (char*)d_ws;
    auto alloc = [&](size_t bytes) {
        off = (off + 15) & ~(size_t)15;
        char* p = base + off;
        off += bytes;
        return p;
    };
    int*   count    = (int*)alloc(sizeof(int) * N_NODES);
    int*   rowptr   = (int*)alloc(sizeof(int) * (N_NODES + 1));
    int*   cursor   = (int*)alloc(sizeof(int) * N_NODES);
    int*   blockSum = (int*)alloc(sizeof(int) * SCAN_NB);
    int2*  pairsSD  = (int2*)alloc(sizeof(int2) * N_EDGES);
    int*   eid      = (int*)alloc(sizeof(int) * N_EDGES);
    float* hA       = (float*)alloc(sizeof(float) * (size_t)N_NODES * F);
    float* hB       = (float*)alloc(sizeof(float) * (size_t)N_NODES * F);
    float* Wf       = (float*)alloc(sizeof(float) * F * 2);
    float* bf       = (float*)alloc(sizeof(float) * 2);
    float* eaP      = (float*)alloc(sizeof(float) * (size_t)N_EDGES * EDIM);
    const int usePerm = (ws_size >= off) ? 1 : 0;

    fuse_weights_kernel<<<1, 128, 0, stream>>>(W1, b1, W2, b2, Wf, bf);

    // CSR build (edge_index is layer-invariant)
    hipMemsetAsync(count, 0, sizeof(int) * N_NODES, stream);
    hist_kernel<<<1024, 256, 0, stream>>>(ei, count);
    scan_partial_kernel<<<SCAN_NB, SCAN_B, 0, stream>>>(count, rowptr, blockSum);
    scan_tops_kernel<<<1, 64, 0, stream>>>(blockSum, rowptr + N_NODES);
    scan_add_kernel<<<SCAN_NB, SCAN_B, 0, stream>>>(blockSum, rowptr, cursor);
    scatter_kernel<<<1024, 256, 0, stream>>>(ei, cursor, pairsSD, eid);
    if (usePerm)
        permute_kernel<<<(N_EDGES * 4 + 255) / 256, 256, 0, stream>>>(
            (const float4*)ea, eid, (float4*)eaP);

    const float* eaSrc = usePerm ? eaP : ea;
    conv_kernel<false><<<NBLK, TPB, 0, stream>>>(x, rowptr, pairsSD, eid, eaSrc, usePerm,
        We + 0 * EDIM * F, be + 0 * F, Wn, bn, Wf, bf, hA, out);
    conv_kernel<false><<<NBLK, TPB, 0, stream>>>(hA, rowptr, pairsSD, eid, eaSrc, usePerm,
        We + 1 * EDIM * F, be + 1 * F, Wn, bn, Wf, bf, hB, out);
    conv_kernel<true><<<NBLK, TPB, 0, stream>>>(hB, rowptr, pairsSD, eid, eaSrc, usePerm,
        We + 2 * EDIM * F, be + 2 * F, Wn, bn, Wf, bf, nullptr, out);
}

// Round 8
// 1212.898 us; speedup vs baseline: 1.8886x; 1.8886x over previous
//
#include <hip/hip_runtime.h>

#define N_NODES 50000
#define N_EDGES 800000
#define F 64
#define EDIM 16
#define NEG_SLOPE 0.01f
#define EPW 64                               // edges per wave (contiguous CSR range)
#define NWAVES_TOT ((N_EDGES + EPW - 1) / EPW)      // 12500
#define EBLK ((NWAVES_TOT + 3) / 4)                 // 3125 blocks of 4 waves
#define NPB 64                               // nodes per block (node kernel)
#define NBLK ((N_NODES + NPB - 1) / NPB)     // 782
#define SCAN_B 1024
#define SCAN_NB ((N_NODES + SCAN_B - 1) / SCAN_B)   // 49

// ---------------- CSR build ----------------
__global__ __launch_bounds__(256) void hist_kernel(const int* __restrict__ ei,
                                                   int* __restrict__ count) {
    for (int e = blockIdx.x * blockDim.x + threadIdx.x; e < N_EDGES;
         e += gridDim.x * blockDim.x)
        atomicAdd(&count[ei[N_EDGES + e]], 1);
}

__global__ __launch_bounds__(SCAN_B) void scan_partial_kernel(const int* __restrict__ count,
                                                              int* __restrict__ rowptr,
                                                              int* __restrict__ blockSum) {
    __shared__ int buf[SCAN_B];
    const int b = blockIdx.x, tid = threadIdx.x;
    const int i = b * SCAN_B + tid;
    int v = (i < N_NODES) ? count[i] : 0;
    buf[tid] = v;
    __syncthreads();
    for (int off = 1; off < SCAN_B; off <<= 1) {
        int t = (tid >= off) ? buf[tid - off] : 0;
        __syncthreads();
        buf[tid] += t;
        __syncthreads();
    }
    if (i < N_NODES) rowptr[i] = buf[tid] - v;      // exclusive within block
    if (tid == SCAN_B - 1) blockSum[b] = buf[tid];
}

__global__ void scan_tops_kernel(int* __restrict__ blockSum, int* __restrict__ rowptrN) {
    const int lane = threadIdx.x;                    // 64 threads = 1 wave
    int v = (lane < SCAN_NB) ? blockSum[lane] : 0;
    int s = v;
    for (int off = 1; off < 64; off <<= 1) {
        int t = __shfl_up(s, off);
        if (lane >= off) s += t;
    }
    if (lane < SCAN_NB) blockSum[lane] = s - v;      // exclusive block offsets
    if (lane == 63) rowptrN[0] = s;
}

__global__ __launch_bounds__(SCAN_B) void scan_add_kernel(const int* __restrict__ blockSum,
                                                          int* __restrict__ rowptr,
                                                          int* __restrict__ cursor) {
    const int i = blockIdx.x * SCAN_B + threadIdx.x;
    if (i < N_NODES) {
        int r = rowptr[i] + blockSum[blockIdx.x];
        rowptr[i] = r;
        cursor[i] = r;
    }
}

// scatter edges into CSR order, copying ea rows along (no separate permute pass)
__global__ __launch_bounds__(256) void scatter_ea_kernel(const int* __restrict__ ei,
                                                         int* __restrict__ cursor,
                                                         const float4* __restrict__ ea4,
                                                         int2* __restrict__ pairsSD,
                                                         float4* __restrict__ eaP4) {
    for (int e = blockIdx.x * blockDim.x + threadIdx.x; e < N_EDGES;
         e += gridDim.x * blockDim.x) {
        int s = ei[e];
        int d = ei[N_EDGES + e];
        int pos = atomicAdd(&cursor[d], 1);
        pairsSD[pos] = make_int2(s, d);
        float4 a0 = ea4[(size_t)e * 4 + 0];
        float4 a1 = ea4[(size_t)e * 4 + 1];
        float4 a2 = ea4[(size_t)e * 4 + 2];
        float4 a3 = ea4[(size_t)e * 4 + 3];
        eaP4[(size_t)pos * 4 + 0] = a0;
        eaP4[(size_t)pos * 4 + 1] = a1;
        eaP4[(size_t)pos * 4 + 2] = a2;
        eaP4[(size_t)pos * 4 + 3] = a3;
    }
}

// ---------------- fuse readout weights ----------------
__global__ void fuse_weights_kernel(
    const float* __restrict__ W1, const float* __restrict__ b1,
    const float* __restrict__ W2, const float* __restrict__ b2,
    float* __restrict__ Wf, float* __restrict__ bf) {
    const int t = threadIdx.x;     // 128 threads
    const int i = t >> 1;
    const int j = t & 1;
    float acc = 0.f;
    for (int k = 0; k < 128; ++k) acc += W1[i * 128 + k] * W2[k * 2 + j];
    Wf[i * 2 + j] = acc;
    if (i == 0) {
        float accb = b2[j];
        for (int k = 0; k < 128; ++k) accb += b1[k] * W2[k * 2 + j];
        bf[j] = accb;
    }
}

// ---------------- edge kernel: segment-accumulate + flush-on-dst-change ----------------
// wave owns EPW contiguous CSR edges; lane = feature; acc holds the running
// segment sum; flush to global aggr (atomic) only when dst changes (~5/wave).
__global__ __launch_bounds__(256) void edge_kernel(
    const float* __restrict__ h,
    const int2* __restrict__ pairsSD,
    const float* __restrict__ eaP,
    const float* __restrict__ We, const float* __restrict__ be,
    float* __restrict__ aggr)
{
    const int lane = threadIdx.x & 63;
    const int gw = (blockIdx.x * 256 + threadIdx.x) >> 6;
    const int r0 = gw * EPW;
    if (r0 >= N_EDGES) return;
    const int r1 = min(r0 + EPW, N_EDGES);

    float weR[EDIM];
#pragma unroll
    for (int k = 0; k < EDIM; ++k) weR[k] = We[k * F + lane];
    const float beR = be[lane];

    int2 sd = pairsSD[r0];
    float hs = h[((size_t)sd.x << 6) + lane];
    int curDst = sd.y;
    float acc = 0.f;

#pragma unroll 1
    for (int j = r0; j < r1; ++j) {
        // depth-1 prefetch of the chained loads (pairs -> h gather)
        const int jn = (j + 1 < r1) ? j + 1 : j;
        int2 sdN = pairsSD[jn];
        float hsN = h[((size_t)sdN.x << 6) + lane];
        // ea row: wave-uniform broadcast float4 stream (CSR order)
        const float4* ep = (const float4*)(eaP + ((size_t)j << 4));
        float4 e0 = ep[0], e1 = ep[1], e2 = ep[2], e3 = ep[3];
        float m = beR;
        m = fmaf(e0.x, weR[0],  m); m = fmaf(e0.y, weR[1],  m);
        m = fmaf(e0.z, weR[2],  m); m = fmaf(e0.w, weR[3],  m);
        m = fmaf(e1.x, weR[4],  m); m = fmaf(e1.y, weR[5],  m);
        m = fmaf(e1.z, weR[6],  m); m = fmaf(e1.w, weR[7],  m);
        m = fmaf(e2.x, weR[8],  m); m = fmaf(e2.y, weR[9],  m);
        m = fmaf(e2.z, weR[10], m); m = fmaf(e2.w, weR[11], m);
        m = fmaf(e3.x, weR[12], m); m = fmaf(e3.y, weR[13], m);
        m = fmaf(e3.z, weR[14], m); m = fmaf(e3.w, weR[15], m);
        if (sd.y != curDst) {                        // wave-uniform branch
            atomicAdd(&aggr[((size_t)curDst << 6) + lane], acc);
            acc = 0.f;
            curDst = sd.y;
        }
        acc += fmaxf(m + hs, 0.f);                   // ReLU
        sd = sdN; hs = hsN;
    }
    atomicAdd(&aggr[((size_t)curDst << 6) + lane], acc);
}

// ---------------- node kernel: t = h + aggr; leaky(t@Wn + bn); LAST fuses readout ----------------
template <bool LAST>
__global__ __launch_bounds__(256) void node_kernel(
    const float* __restrict__ h, const float* __restrict__ aggr,
    const float* __restrict__ Wn, const float* __restrict__ bn,
    const float* __restrict__ Wf, const float* __restrict__ bf,
    float* __restrict__ hout, float* __restrict__ out)
{
    __shared__ float tS[NPB * F];   // 16 KB
    const int tid  = threadIdx.x;
    const int lane = tid & 63;
    const int wid  = tid >> 6;
    const int n0   = blockIdx.x * NPB;
    const int nCnt = min(NPB, N_NODES - n0);

    // stage t = h + aggr (coalesced float4), zero-pad the tail
    {
        float4* t4 = (float4*)tS;
        const float4* h4 = (const float4*)(h + ((size_t)n0 << 6));
        const float4* a4 = (const float4*)(aggr + ((size_t)n0 << 6));
        for (int i = tid; i < NPB * F / 4; i += 256) {
            if ((i >> 4) < nCnt) {
                float4 hv = h4[i], av = a4[i];
                t4[i] = make_float4(hv.x + av.x, hv.y + av.y, hv.z + av.z, hv.w + av.w);
            } else {
                t4[i] = make_float4(0.f, 0.f, 0.f, 0.f);
            }
        }
    }
    __syncthreads();

    // wave handles 16 nodes; Wn coalesced; t via wave-uniform b128 broadcasts
    const int nb = wid * 16;
    const float bnR = bn[lane];
    float accv[16];
#pragma unroll
    for (int i = 0; i < 16; ++i) accv[i] = bnR;
#pragma unroll
    for (int q = 0; q < 16; ++q) {
        const float w0 = Wn[(4 * q + 0) * F + lane];
        const float w1 = Wn[(4 * q + 1) * F + lane];
        const float w2 = Wn[(4 * q + 2) * F + lane];
        const float w3 = Wn[(4 * q + 3) * F + lane];
#pragma unroll
        for (int i = 0; i < 16; ++i) {
            const float4 t4 = *(const float4*)&tS[((nb + i) << 6) + (q << 2)];
            accv[i] = fmaf(t4.w, w3, fmaf(t4.z, w2, fmaf(t4.y, w1, fmaf(t4.x, w0, accv[i]))));
        }
    }
    float wf0 = 0.f, wf1 = 0.f, bf0 = 0.f, bf1 = 0.f;
    if (LAST) { wf0 = Wf[lane * 2]; wf1 = Wf[lane * 2 + 1]; bf0 = bf[0]; bf1 = bf[1]; }
#pragma unroll
    for (int i = 0; i < 16; ++i) {
        const int nl = nb + i;
        if (nl >= nCnt) break;
        float acc = accv[i];
        acc = acc >= 0.f ? acc : NEG_SLOPE * acc;    // LeakyReLU
        if (!LAST) {
            hout[((size_t)(n0 + nl) << 6) + lane] = acc;
        } else {
            float v0 = acc * wf0, v1 = acc * wf1;
#pragma unroll
            for (int off = 32; off; off >>= 1) {
                v0 += __shfl_down(v0, off);
                v1 += __shfl_down(v1, off);
            }
            if (lane == 0) {
                out[(n0 + nl) * 2 + 0] = v0 + bf0;
                out[(n0 + nl) * 2 + 1] = v1 + bf1;
            }
        }
    }
}

extern "C" void kernel_launch(void* const* d_in, const int* in_sizes, int n_in,
                              void* d_out, int out_size, void* d_ws, size_t ws_size,
                              hipStream_t stream) {
    const float* x  = (const float*)d_in[0];
    const int*   ei = (const int*)d_in[1];       // int32 per harness contract
    const float* ea = (const float*)d_in[2];
    const float* Wn = (const float*)d_in[3];
    const float* bn = (const float*)d_in[4];
    const float* We = (const float*)d_in[5];     // [3,16,64]
    const float* be = (const float*)d_in[6];     // [3,64]
    const float* W1 = (const float*)d_in[7];
    const float* b1 = (const float*)d_in[8];
    const float* W2 = (const float*)d_in[9];
    const float* b2 = (const float*)d_in[10];
    float* out = (float*)d_out;

    size_t off = 0;
    char* base = (char*)d_ws;
    auto alloc = [&](size_t bytes) {
        off = (off + 255) & ~(size_t)255;
        char* p = base + off;
        off += bytes;
        return p;
    };
    int*   count    = (int*)alloc(sizeof(int) * N_NODES);
    int*   rowptr   = (int*)alloc(sizeof(int) * (N_NODES + 1));
    int*   cursor   = (int*)alloc(sizeof(int) * N_NODES);
    int*   blockSum = (int*)alloc(sizeof(int) * SCAN_NB);
    int2*  pairsSD  = (int2*)alloc(sizeof(int2) * N_EDGES);
    float* eaP      = (float*)alloc(sizeof(float) * (size_t)N_EDGES * EDIM);
    float* aggr     = (float*)alloc(sizeof(float) * (size_t)N_NODES * F);
    float* hA       = (float*)alloc(sizeof(float) * (size_t)N_NODES * F);
    float* hB       = (float*)alloc(sizeof(float) * (size_t)N_NODES * F);
    float* Wf       = (float*)alloc(sizeof(float) * F * 2);
    float* bf       = (float*)alloc(sizeof(float) * 2);

    fuse_weights_kernel<<<1, 128, 0, stream>>>(W1, b1, W2, b2, Wf, bf);

    // CSR build (edge_index layer-invariant; ea copied into CSR order here too)
    hipMemsetAsync(count, 0, sizeof(int) * N_NODES, stream);
    hist_kernel<<<1024, 256, 0, stream>>>(ei, count);
    scan_partial_kernel<<<SCAN_NB, SCAN_B, 0, stream>>>(count, rowptr, blockSum);
    scan_tops_kernel<<<1, 64, 0, stream>>>(blockSum, rowptr + N_NODES);
    scan_add_kernel<<<SCAN_NB, SCAN_B, 0, stream>>>(blockSum, rowptr, cursor);
    scatter_ea_kernel<<<1024, 256, 0, stream>>>(ei, cursor, (const float4*)ea,
                                                pairsSD, (float4*)eaP);

    const float* hcur = x;
    float* houts[3] = {hA, hB, nullptr};
    for (int l = 0; l < 3; ++l) {
        hipMemsetAsync(aggr, 0, sizeof(float) * (size_t)N_NODES * F, stream);
        edge_kernel<<<EBLK, 256, 0, stream>>>(hcur, pairsSD, eaP,
                                              We + (size_t)l * EDIM * F,
                                              be + (size_t)l * F, aggr);
        if (l < 2) {
            node_kernel<false><<<NBLK, 256, 0, stream>>>(hcur, aggr, Wn, bn,
                                                         Wf, bf, houts[l], out);
            hcur = houts[l];
        } else {
            node_kernel<true><<<NBLK, 256, 0, stream>>>(hcur, aggr, Wn, bn,
                                                        Wf, bf, nullptr, out);
        }
    }
}

// Round 9
// 596.813 us; speedup vs baseline: 3.8383x; 2.0323x over previous
//
#include <hip/hip_runtime.h>

#define N_NODES 50000
#define N_EDGES 800000
#define F 64
#define EDIM 16
#define NEG_SLOPE 0.01f
#define EPW 64                               // edges per wave (contiguous CSR range)
#define NWAVES_TOT ((N_EDGES + EPW - 1) / EPW)      // 12500
#define EBLK ((NWAVES_TOT + 3) / 4)                 // 3125 blocks of 4 waves
#define NPB 32                               // nodes per block (node kernel)
#define NBLK ((N_NODES + NPB - 1) / NPB)     // 1563
#define NPW 8                                // nodes per wave (node kernel)
#define SCAN_B 1024
#define SCAN_NB ((N_NODES + SCAN_B - 1) / SCAN_B)   // 49

// ---------------- CSR build ----------------
__global__ __launch_bounds__(256) void hist_kernel(const int* __restrict__ ei,
                                                   int* __restrict__ count) {
    for (int e = blockIdx.x * blockDim.x + threadIdx.x; e < N_EDGES;
         e += gridDim.x * blockDim.x)
        atomicAdd(&count[ei[N_EDGES + e]], 1);
}

__global__ __launch_bounds__(SCAN_B) void scan_partial_kernel(const int* __restrict__ count,
                                                              int* __restrict__ rowptr,
                                                              int* __restrict__ blockSum) {
    __shared__ int buf[SCAN_B];
    const int b = blockIdx.x, tid = threadIdx.x;
    const int i = b * SCAN_B + tid;
    int v = (i < N_NODES) ? count[i] : 0;
    buf[tid] = v;
    __syncthreads();
    for (int off = 1; off < SCAN_B; off <<= 1) {
        int t = (tid >= off) ? buf[tid - off] : 0;
        __syncthreads();
        buf[tid] += t;
        __syncthreads();
    }
    if (i < N_NODES) rowptr[i] = buf[tid] - v;      // exclusive within block
    if (tid == SCAN_B - 1) blockSum[b] = buf[tid];
}

__global__ void scan_tops_kernel(int* __restrict__ blockSum, int* __restrict__ rowptrN) {
    const int lane = threadIdx.x;                    // 64 threads = 1 wave
    int v = (lane < SCAN_NB) ? blockSum[lane] : 0;
    int s = v;
    for (int off = 1; off < 64; off <<= 1) {
        int t = __shfl_up(s, off);
        if (lane >= off) s += t;
    }
    if (lane < SCAN_NB) blockSum[lane] = s - v;      // exclusive block offsets
    if (lane == 63) rowptrN[0] = s;
}

__global__ __launch_bounds__(SCAN_B) void scan_add_kernel(const int* __restrict__ blockSum,
                                                          int* __restrict__ rowptr,
                                                          int* __restrict__ cursor) {
    const int i = blockIdx.x * SCAN_B + threadIdx.x;
    if (i < N_NODES) {
        int r = rowptr[i] + blockSum[blockIdx.x];
        rowptr[i] = r;
        cursor[i] = r;
    }
}

// scatter edges into CSR order, copying ea rows along (no separate permute pass)
__global__ __launch_bounds__(256) void scatter_ea_kernel(const int* __restrict__ ei,
                                                         int* __restrict__ cursor,
                                                         const float4* __restrict__ ea4,
                                                         int2* __restrict__ pairsSD,
                                                         float4* __restrict__ eaP4) {
    for (int e = blockIdx.x * blockDim.x + threadIdx.x; e < N_EDGES;
         e += gridDim.x * blockDim.x) {
        int s = ei[e];
        int d = ei[N_EDGES + e];
        int pos = atomicAdd(&cursor[d], 1);
        pairsSD[pos] = make_int2(s, d);
        float4 a0 = ea4[(size_t)e * 4 + 0];
        float4 a1 = ea4[(size_t)e * 4 + 1];
        float4 a2 = ea4[(size_t)e * 4 + 2];
        float4 a3 = ea4[(size_t)e * 4 + 3];
        eaP4[(size_t)pos * 4 + 0] = a0;
        eaP4[(size_t)pos * 4 + 1] = a1;
        eaP4[(size_t)pos * 4 + 2] = a2;
        eaP4[(size_t)pos * 4 + 3] = a3;
    }
}

// ---------------- fuse readout weights ----------------
__global__ void fuse_weights_kernel(
    const float* __restrict__ W1, const float* __restrict__ b1,
    const float* __restrict__ W2, const float* __restrict__ b2,
    float* __restrict__ Wf, float* __restrict__ bf) {
    const int t = threadIdx.x;     // 128 threads
    const int i = t >> 1;
    const int j = t & 1;
    float acc = 0.f;
    for (int k = 0; k < 128; ++k) acc += W1[i * 128 + k] * W2[k * 2 + j];
    Wf[i * 2 + j] = acc;
    if (i == 0) {
        float accb = b2[j];
        for (int k = 0; k < 128; ++k) accb += b1[k] * W2[k * 2 + j];
        bf[j] = accb;
    }
}

// ---------------- edge kernel: segment-accumulate + flush-on-dst-change ----------------
__global__ __launch_bounds__(256) void edge_kernel(
    const float* __restrict__ h,
    const int2* __restrict__ pairsSD,
    const float* __restrict__ eaP,
    const float* __restrict__ We, const float* __restrict__ be,
    float* __restrict__ aggr)
{
    const int lane = threadIdx.x & 63;
    const int gw = (blockIdx.x * 256 + threadIdx.x) >> 6;
    const int r0 = gw * EPW;
    if (r0 >= N_EDGES) return;
    const int r1 = min(r0 + EPW, N_EDGES);

    float weR[EDIM];
#pragma unroll
    for (int k = 0; k < EDIM; ++k) weR[k] = We[k * F + lane];
    const float beR = be[lane];

    int2 sd = pairsSD[r0];
    float hs = h[((size_t)sd.x << 6) + lane];
    int curDst = sd.y;
    float acc = 0.f;

#pragma unroll 1
    for (int j = r0; j < r1; ++j) {
        // depth-1 prefetch of the chained loads (pairs -> h gather)
        const int jn = (j + 1 < r1) ? j + 1 : j;
        int2 sdN = pairsSD[jn];
        float hsN = h[((size_t)sdN.x << 6) + lane];
        // ea row: wave-uniform broadcast float4 stream (CSR order)
        const float4* ep = (const float4*)(eaP + ((size_t)j << 4));
        float4 e0 = ep[0], e1 = ep[1], e2 = ep[2], e3 = ep[3];
        float m = beR;
        m = fmaf(e0.x, weR[0],  m); m = fmaf(e0.y, weR[1],  m);
        m = fmaf(e0.z, weR[2],  m); m = fmaf(e0.w, weR[3],  m);
        m = fmaf(e1.x, weR[4],  m); m = fmaf(e1.y, weR[5],  m);
        m = fmaf(e1.z, weR[6],  m); m = fmaf(e1.w, weR[7],  m);
        m = fmaf(e2.x, weR[8],  m); m = fmaf(e2.y, weR[9],  m);
        m = fmaf(e2.z, weR[10], m); m = fmaf(e2.w, weR[11], m);
        m = fmaf(e3.x, weR[12], m); m = fmaf(e3.y, weR[13], m);
        m = fmaf(e3.z, weR[14], m); m = fmaf(e3.w, weR[15], m);
        if (sd.y != curDst) {                        // wave-uniform branch
            atomicAdd(&aggr[((size_t)curDst << 6) + lane], acc);
            acc = 0.f;
            curDst = sd.y;
        }
        acc += fmaxf(m + hs, 0.f);                   // ReLU
        sd = sdN; hs = hsN;
    }
    atomicAdd(&aggr[((size_t)curDst << 6) + lane], acc);
}

// ---------------- node kernel: t = h + aggr; leaky(t@Wn + bn); LAST fuses readout ----------------
// Wn staged in LDS (keeps register pressure low -- global Wn loads in the
// unrolled loop get hoisted en masse by the scheduler and spill; LDS reads don't).
template <bool LAST>
__global__ __launch_bounds__(256) void node_kernel(
    const float* __restrict__ h, const float* __restrict__ aggr,
    const float* __restrict__ Wn, const float* __restrict__ bn,
    const float* __restrict__ Wf, const float* __restrict__ bf,
    float* __restrict__ hout, float* __restrict__ out)
{
    __shared__ float WnS[F * F];    // 16 KB
    __shared__ float tS[NPB * F];   // 8 KB
    const int tid  = threadIdx.x;
    const int lane = tid & 63;
    const int wid  = tid >> 6;
    const int n0   = blockIdx.x * NPB;
    const int nCnt = min(NPB, N_NODES - n0);

    {   // stage Wn (coalesced float4)
        const float4* s4 = (const float4*)Wn;
        float4* d4 = (float4*)WnS;
        for (int i = tid; i < F * F / 4; i += 256) d4[i] = s4[i];
    }
    {   // stage t = h + aggr (coalesced float4), zero-pad the tail
        float4* t4 = (float4*)tS;
        const float4* h4 = (const float4*)(h + ((size_t)n0 << 6));
        const float4* a4 = (const float4*)(aggr + ((size_t)n0 << 6));
        for (int i = tid; i < NPB * F / 4; i += 256) {
            if ((i >> 4) < nCnt) {
                float4 hv = h4[i], av = a4[i];
                t4[i] = make_float4(hv.x + av.x, hv.y + av.y, hv.z + av.z, hv.w + av.w);
            } else {
                t4[i] = make_float4(0.f, 0.f, 0.f, 0.f);
            }
        }
    }
    __syncthreads();

    // wave handles 8 nodes; Wn cols + t rows both from LDS
    const int nb = wid * NPW;
    const float bnR = bn[lane];
    float accv[NPW];
#pragma unroll
    for (int i = 0; i < NPW; ++i) accv[i] = bnR;
#pragma unroll
    for (int q = 0; q < 16; ++q) {
        const float w0 = WnS[(4 * q + 0) * F + lane];
        const float w1 = WnS[(4 * q + 1) * F + lane];
        const float w2 = WnS[(4 * q + 2) * F + lane];
        const float w3 = WnS[(4 * q + 3) * F + lane];
#pragma unroll
        for (int i = 0; i < NPW; ++i) {
            const float4 t4 = *(const float4*)&tS[((nb + i) << 6) + (q << 2)];
            accv[i] = fmaf(t4.w, w3, fmaf(t4.z, w2, fmaf(t4.y, w1, fmaf(t4.x, w0, accv[i]))));
        }
    }
    float wf0 = 0.f, wf1 = 0.f, bf0 = 0.f, bf1 = 0.f;
    if (LAST) { wf0 = Wf[lane * 2]; wf1 = Wf[lane * 2 + 1]; bf0 = bf[0]; bf1 = bf[1]; }
#pragma unroll
    for (int i = 0; i < NPW; ++i) {
        const int nl = nb + i;
        if (nl >= nCnt) break;
        float acc = accv[i];
        acc = acc >= 0.f ? acc : NEG_SLOPE * acc;    // LeakyReLU
        if (!LAST) {
            hout[((size_t)(n0 + nl) << 6) + lane] = acc;
        } else {
            float v0 = acc * wf0, v1 = acc * wf1;
#pragma unroll
            for (int off = 32; off; off >>= 1) {
                v0 += __shfl_down(v0, off);
                v1 += __shfl_down(v1, off);
            }
            if (lane == 0) {
                out[(n0 + nl) * 2 + 0] = v0 + bf0;
                out[(n0 + nl) * 2 + 1] = v1 + bf1;
            }
        }
    }
}

extern "C" void kernel_launch(void* const* d_in, const int* in_sizes, int n_in,
                              void* d_out, int out_size, void* d_ws, size_t ws_size,
                              hipStream_t stream) {
    const float* x  = (const float*)d_in[0];
    const int*   ei = (const int*)d_in[1];       // int32 per harness contract
    const float* ea = (const float*)d_in[2];
    const float* Wn = (const float*)d_in[3];
    const float* bn = (const float*)d_in[4];
    const float* We = (const float*)d_in[5];     // [3,16,64]
    const float* be = (const float*)d_in[6];     // [3,64]
    const float* W1 = (const float*)d_in[7];
    const float* b1 = (const float*)d_in[8];
    const float* W2 = (const float*)d_in[9];
    const float* b2 = (const float*)d_in[10];
    float* out = (float*)d_out;

    size_t off = 0;
    char* base = (char*)d_ws;
    auto alloc = [&](size_t bytes) {
        off = (off + 255) & ~(size_t)255;
        char* p = base + off;
        off += bytes;
        return p;
    };
    int*   count    = (int*)alloc(sizeof(int) * N_NODES);
    int*   rowptr   = (int*)alloc(sizeof(int) * (N_NODES + 1));
    int*   cursor   = (int*)alloc(sizeof(int) * N_NODES);
    int*   blockSum = (int*)alloc(sizeof(int) * SCAN_NB);
    int2*  pairsSD  = (int2*)alloc(sizeof(int2) * N_EDGES);
    float* eaP      = (float*)alloc(sizeof(float) * (size_t)N_EDGES * EDIM);
    float* aggr     = (float*)alloc(sizeof(float) * (size_t)N_NODES * F);
    float* hA       = (float*)alloc(sizeof(float) * (size_t)N_NODES * F);
    float* hB       = (float*)alloc(sizeof(float) * (size_t)N_NODES * F);
    float* Wf       = (float*)alloc(sizeof(float) * F * 2);
    float* bf       = (float*)alloc(sizeof(float) * 2);

    fuse_weights_kernel<<<1, 128, 0, stream>>>(W1, b1, W2, b2, Wf, bf);

    // CSR build (edge_index layer-invariant; ea copied into CSR order here too)
    hipMemsetAsync(count, 0, sizeof(int) * N_NODES, stream);
    hist_kernel<<<1024, 256, 0, stream>>>(ei, count);
    scan_partial_kernel<<<SCAN_NB, SCAN_B, 0, stream>>>(count, rowptr, blockSum);
    scan_tops_kernel<<<1, 64, 0, stream>>>(blockSum, rowptr + N_NODES);
    scan_add_kernel<<<SCAN_NB, SCAN_B, 0, stream>>>(blockSum, rowptr, cursor);
    scatter_ea_kernel<<<1024, 256, 0, stream>>>(ei, cursor, (const float4*)ea,
                                                pairsSD, (float4*)eaP);

    const float* hcur = x;
    float* houts[3] = {hA, hB, nullptr};
    for (int l = 0; l < 3; ++l) {
        hipMemsetAsync(aggr, 0, sizeof(float) * (size_t)N_NODES * F, stream);
        edge_kernel<<<EBLK, 256, 0, stream>>>(hcur, pairsSD, eaP,
                                              We + (size_t)l * EDIM * F,
                                              be + (size_t)l * F, aggr);
        if (l < 2) {
            node_kernel<false><<<NBLK, 256, 0, stream>>>(hcur, aggr, Wn, bn,
                                                         Wf, bf, houts[l], out);
            hcur = houts[l];
        } else {
            node_kernel<true><<<NBLK, 256, 0, stream>>>(hcur, aggr, Wn, bn,
                                                        Wf, bf, nullptr, out);
        }
    }
}

// Round 10
// 570.105 us; speedup vs baseline: 4.0181x; 1.0468x over previous
//
#include <hip/hip_runtime.h>

#define N_NODES 50000
#define N_EDGES 800000
#define F 64
#define EDIM 16
#define NEG_SLOPE 0.01f
#define EPW 64                               // edges per wave (contiguous CSR range)
#define NWAVES_TOT ((N_EDGES + EPW - 1) / EPW)      // 12500
#define EBLK ((NWAVES_TOT + 3) / 4)                 // 3125 blocks of 4 waves
#define NPB 32                               // nodes per block (node kernel)
#define NBLK ((N_NODES + NPB - 1) / NPB)     // 1563
#define NPW 8                                // nodes per wave (node kernel)
#define SCAN_B 1024
#define SCAN_NB ((N_NODES + SCAN_B - 1) / SCAN_B)   // 49

// ---------------- CSR build ----------------
__global__ __launch_bounds__(256) void hist_kernel(const int* __restrict__ ei,
                                                   int* __restrict__ count) {
    for (int e = blockIdx.x * blockDim.x + threadIdx.x; e < N_EDGES;
         e += gridDim.x * blockDim.x)
        atomicAdd(&count[ei[N_EDGES + e]], 1);
}

__global__ __launch_bounds__(SCAN_B) void scan_partial_kernel(const int* __restrict__ count,
                                                              int* __restrict__ rowptr,
                                                              int* __restrict__ blockSum) {
    __shared__ int buf[SCAN_B];
    const int b = blockIdx.x, tid = threadIdx.x;
    const int i = b * SCAN_B + tid;
    int v = (i < N_NODES) ? count[i] : 0;
    buf[tid] = v;
    __syncthreads();
    for (int off = 1; off < SCAN_B; off <<= 1) {
        int t = (tid >= off) ? buf[tid - off] : 0;
        __syncthreads();
        buf[tid] += t;
        __syncthreads();
    }
    if (i < N_NODES) rowptr[i] = buf[tid] - v;      // exclusive within block
    if (tid == SCAN_B - 1) blockSum[b] = buf[tid];
}

__global__ void scan_tops_kernel(int* __restrict__ blockSum, int* __restrict__ rowptrN) {
    const int lane = threadIdx.x;                    // 64 threads = 1 wave
    int v = (lane < SCAN_NB) ? blockSum[lane] : 0;
    int s = v;
    for (int off = 1; off < 64; off <<= 1) {
        int t = __shfl_up(s, off);
        if (lane >= off) s += t;
    }
    if (lane < SCAN_NB) blockSum[lane] = s - v;      // exclusive block offsets
    if (lane == 63) rowptrN[0] = s;
}

__global__ __launch_bounds__(SCAN_B) void scan_add_kernel(const int* __restrict__ blockSum,
                                                          int* __restrict__ rowptr,
                                                          int* __restrict__ cursor) {
    const int i = blockIdx.x * SCAN_B + threadIdx.x;
    if (i < N_NODES) {
        int r = rowptr[i] + blockSum[blockIdx.x];
        rowptr[i] = r;
        cursor[i] = r;
    }
}

// scatter edges into CSR order, copying ea rows along (no separate permute pass)
__global__ __launch_bounds__(256) void scatter_ea_kernel(const int* __restrict__ ei,
                                                         int* __restrict__ cursor,
                                                         const float4* __restrict__ ea4,
                                                         int2* __restrict__ pairsSD,
                                                         float4* __restrict__ eaP4) {
    for (int e = blockIdx.x * blockDim.x + threadIdx.x; e < N_EDGES;
         e += gridDim.x * blockDim.x) {
        int s = ei[e];
        int d = ei[N_EDGES + e];
        int pos = atomicAdd(&cursor[d], 1);
        pairsSD[pos] = make_int2(s, d);
        float4 a0 = ea4[(size_t)e * 4 + 0];
        float4 a1 = ea4[(size_t)e * 4 + 1];
        float4 a2 = ea4[(size_t)e * 4 + 2];
        float4 a3 = ea4[(size_t)e * 4 + 3];
        eaP4[(size_t)pos * 4 + 0] = a0;
        eaP4[(size_t)pos * 4 + 1] = a1;
        eaP4[(size_t)pos * 4 + 2] = a2;
        eaP4[(size_t)pos * 4 + 3] = a3;
    }
}

// ---------------- fuse readout weights ----------------
__global__ void fuse_weights_kernel(
    const float* __restrict__ W1, const float* __restrict__ b1,
    const float* __restrict__ W2, const float* __restrict__ b2,
    float* __restrict__ Wf, float* __restrict__ bf) {
    const int t = threadIdx.x;     // 128 threads
    const int i = t >> 1;
    const int j = t & 1;
    float acc = 0.f;
    for (int k = 0; k < 128; ++k) acc += W1[i * 128 + k] * W2[k * 2 + j];
    Wf[i * 2 + j] = acc;
    if (i == 0) {
        float accb = b2[j];
        for (int k = 0; k < 128; ++k) accb += b1[k] * W2[k * 2 + j];
        bf[j] = accb;
    }
}

// ---------------- edge kernel: segment-accumulate, pairs depth-3 / h depth-2 pipeline ----------------
__global__ __launch_bounds__(256) void edge_kernel(
    const float* __restrict__ h,
    const int2* __restrict__ pairsSD,
    const float* __restrict__ eaP,
    const float* __restrict__ We, const float* __restrict__ be,
    float* __restrict__ aggr)
{
    const int lane = threadIdx.x & 63;
    const int gw = (blockIdx.x * 256 + threadIdx.x) >> 6;
    const int r0 = gw * EPW;
    if (r0 >= N_EDGES) return;
    const int r1 = min(r0 + EPW, N_EDGES);

    float weR[EDIM];
#pragma unroll
    for (int k = 0; k < EDIM; ++k) weR[k] = We[k * F + lane];
    const float beR = be[lane];

    // prologue: pairs 3 ahead, h 2 ahead (named regs, shift pattern)
    int2 sdA = pairsSD[r0];
    int2 sdB = pairsSD[min(r0 + 1, r1 - 1)];
    int2 sdC = pairsSD[min(r0 + 2, r1 - 1)];
    float hsA = h[((size_t)sdA.x << 6) + lane];
    float hsB = h[((size_t)sdB.x << 6) + lane];

    int curDst = sdA.y;
    float acc = 0.f;

#pragma unroll 2
    for (int j = r0; j < r1; ++j) {
        // issue next-next-next pairs and next-next h (addresses 2+ iters old)
        int2 sdD = pairsSD[min(j + 3, r1 - 1)];
        float hsC = h[((size_t)sdC.x << 6) + lane];
        // ea row: wave-uniform broadcast float4 stream (CSR order)
        const float4* ep = (const float4*)(eaP + ((size_t)j << 4));
        float4 e0 = ep[0], e1 = ep[1], e2 = ep[2], e3 = ep[3];
        float m = beR;
        m = fmaf(e0.x, weR[0],  m); m = fmaf(e0.y, weR[1],  m);
        m = fmaf(e0.z, weR[2],  m); m = fmaf(e0.w, weR[3],  m);
        m = fmaf(e1.x, weR[4],  m); m = fmaf(e1.y, weR[5],  m);
        m = fmaf(e1.z, weR[6],  m); m = fmaf(e1.w, weR[7],  m);
        m = fmaf(e2.x, weR[8],  m); m = fmaf(e2.y, weR[9],  m);
        m = fmaf(e2.z, weR[10], m); m = fmaf(e2.w, weR[11], m);
        m = fmaf(e3.x, weR[12], m); m = fmaf(e3.y, weR[13], m);
        m = fmaf(e3.z, weR[14], m); m = fmaf(e3.w, weR[15], m);
        if (sdA.y != curDst) {                       // wave-uniform branch
            atomicAdd(&aggr[((size_t)curDst << 6) + lane], acc);
            acc = 0.f;
            curDst = sdA.y;
        }
        acc += fmaxf(m + hsA, 0.f);                  // ReLU
        sdA = sdB; sdB = sdC; sdC = sdD;
        hsA = hsB; hsB = hsC;
    }
    atomicAdd(&aggr[((size_t)curDst << 6) + lane], acc);
}

// ---------------- node kernel: t = h + aggr; leaky(t@Wn + bn); LAST fuses readout ----------------
// Register discipline: hard cap via launch_bounds + bounded unroll window
// (full unroll let the scheduler hoist all 192 LDS loads -> 256 VGPR + spills).
template <bool LAST>
__global__ __launch_bounds__(256, 4) void node_kernel(
    const float* __restrict__ h, const float* __restrict__ aggr,
    const float* __restrict__ Wn, const float* __restrict__ bn,
    const float* __restrict__ Wf, const float* __restrict__ bf,
    float* __restrict__ hout, float* __restrict__ out)
{
    __shared__ float WnS[F * F];    // 16 KB
    __shared__ float tS[NPB * F];   // 8 KB
    const int tid  = threadIdx.x;
    const int lane = tid & 63;
    const int wid  = tid >> 6;
    const int n0   = blockIdx.x * NPB;
    const int nCnt = min(NPB, N_NODES - n0);

    {   // stage Wn (coalesced float4)
        const float4* s4 = (const float4*)Wn;
        float4* d4 = (float4*)WnS;
        for (int i = tid; i < F * F / 4; i += 256) d4[i] = s4[i];
    }
    {   // stage t = h + aggr (coalesced float4), zero-pad the tail
        float4* t4 = (float4*)tS;
        const float4* h4 = (const float4*)(h + ((size_t)n0 << 6));
        const float4* a4 = (const float4*)(aggr + ((size_t)n0 << 6));
        for (int i = tid; i < NPB * F / 4; i += 256) {
            if ((i >> 4) < nCnt) {
                float4 hv = h4[i], av = a4[i];
                t4[i] = make_float4(hv.x + av.x, hv.y + av.y, hv.z + av.z, hv.w + av.w);
            } else {
                t4[i] = make_float4(0.f, 0.f, 0.f, 0.f);
            }
        }
    }
    __syncthreads();

    // wave handles 8 nodes; Wn cols + t rows both from LDS; bounded unroll
    const int nb = wid * NPW;
    const float bnR = bn[lane];
    float accv[NPW];
#pragma unroll
    for (int i = 0; i < NPW; ++i) accv[i] = bnR;
#pragma unroll 4
    for (int q = 0; q < 16; ++q) {
        const float w0 = WnS[(4 * q + 0) * F + lane];
        const float w1 = WnS[(4 * q + 1) * F + lane];
        const float w2 = WnS[(4 * q + 2) * F + lane];
        const float w3 = WnS[(4 * q + 3) * F + lane];
#pragma unroll
        for (int i = 0; i < NPW; ++i) {
            const float4 t4 = *(const float4*)&tS[((nb + i) << 6) + (q << 2)];
            accv[i] = fmaf(t4.w, w3, fmaf(t4.z, w2, fmaf(t4.y, w1, fmaf(t4.x, w0, accv[i]))));
        }
    }
    float wf0 = 0.f, wf1 = 0.f, bf0 = 0.f, bf1 = 0.f;
    if (LAST) { wf0 = Wf[lane * 2]; wf1 = Wf[lane * 2 + 1]; bf0 = bf[0]; bf1 = bf[1]; }
#pragma unroll
    for (int i = 0; i < NPW; ++i) {
        const int nl = nb + i;
        if (nl >= nCnt) break;
        float acc = accv[i];
        acc = acc >= 0.f ? acc : NEG_SLOPE * acc;    // LeakyReLU
        if (!LAST) {
            hout[((size_t)(n0 + nl) << 6) + lane] = acc;
        } else {
            float v0 = acc * wf0, v1 = acc * wf1;
#pragma unroll
            for (int off = 32; off; off >>= 1) {
                v0 += __shfl_down(v0, off);
                v1 += __shfl_down(v1, off);
            }
            if (lane == 0) {
                out[(n0 + nl) * 2 + 0] = v0 + bf0;
                out[(n0 + nl) * 2 + 1] = v1 + bf1;
            }
        }
    }
}

extern "C" void kernel_launch(void* const* d_in, const int* in_sizes, int n_in,
                              void* d_out, int out_size, void* d_ws, size_t ws_size,
                              hipStream_t stream) {
    const float* x  = (const float*)d_in[0];
    const int*   ei = (const int*)d_in[1];       // int32 per harness contract
    const float* ea = (const float*)d_in[2];
    const float* Wn = (const float*)d_in[3];
    const float* bn = (const float*)d_in[4];
    const float* We = (const float*)d_in[5];     // [3,16,64]
    const float* be = (const float*)d_in[6];     // [3,64]
    const float* W1 = (const float*)d_in[7];
    const float* b1 = (const float*)d_in[8];
    const float* W2 = (const float*)d_in[9];
    const float* b2 = (const float*)d_in[10];
    float* out = (float*)d_out;

    size_t off = 0;
    char* base = (char*)d_ws;
    auto alloc = [&](size_t bytes) {
        off = (off + 255) & ~(size_t)255;
        char* p = base + off;
        off += bytes;
        return p;
    };
    int*   count    = (int*)alloc(sizeof(int) * N_NODES);
    int*   rowptr   = (int*)alloc(sizeof(int) * (N_NODES + 1));
    int*   cursor   = (int*)alloc(sizeof(int) * N_NODES);
    int*   blockSum = (int*)alloc(sizeof(int) * SCAN_NB);
    int2*  pairsSD  = (int2*)alloc(sizeof(int2) * N_EDGES);
    float* eaP      = (float*)alloc(sizeof(float) * (size_t)N_EDGES * EDIM);
    float* aggr     = (float*)alloc(sizeof(float) * (size_t)N_NODES * F);
    float* hA       = (float*)alloc(sizeof(float) * (size_t)N_NODES * F);
    float* hB       = (float*)alloc(sizeof(float) * (size_t)N_NODES * F);
    float* Wf       = (float*)alloc(sizeof(float) * F * 2);
    float* bf       = (float*)alloc(sizeof(float) * 2);

    fuse_weights_kernel<<<1, 128, 0, stream>>>(W1, b1, W2, b2, Wf, bf);

    // CSR build (edge_index layer-invariant; ea copied into CSR order here too)
    hipMemsetAsync(count, 0, sizeof(int) * N_NODES, stream);
    hist_kernel<<<1024, 256, 0, stream>>>(ei, count);
    scan_partial_kernel<<<SCAN_NB, SCAN_B, 0, stream>>>(count, rowptr, blockSum);
    scan_tops_kernel<<<1, 64, 0, stream>>>(blockSum, rowptr + N_NODES);
    scan_add_kernel<<<SCAN_NB, SCAN_B, 0, stream>>>(blockSum, rowptr, cursor);
    scatter_ea_kernel<<<1024, 256, 0, stream>>>(ei, cursor, (const float4*)ea,
                                                pairsSD, (float4*)eaP);

    const float* hcur = x;
    float* houts[3] = {hA, hB, nullptr};
    for (int l = 0; l < 3; ++l) {
        hipMemsetAsync(aggr, 0, sizeof(float) * (size_t)N_NODES * F, stream);
        edge_kernel<<<EBLK, 256, 0, stream>>>(hcur, pairsSD, eaP,
                                              We + (size_t)l * EDIM * F,
                                              be + (size_t)l * F, aggr);
        if (l < 2) {
            node_kernel<false><<<NBLK, 256, 0, stream>>>(hcur, aggr, Wn, bn,
                                                         Wf, bf, houts[l], out);
            hcur = houts[l];
        } else {
            node_kernel<true><<<NBLK, 256, 0, stream>>>(hcur, aggr, Wn, bn,
                                                        Wf, bf, nullptr, out);
        }
    }
}

// Round 11
// 568.105 us; speedup vs baseline: 4.0322x; 1.0035x over previous
//
#include <hip/hip_runtime.h>

#define N_NODES 50000
#define N_EDGES 800000
#define F 64
#define EDIM 16
#define NEG_SLOPE 0.01f
#define EPW 32                               // edges per wave (contiguous CSR range)
#define NWAVES_TOT ((N_EDGES + EPW - 1) / EPW)      // 25000
#define EBLK ((NWAVES_TOT + 3) / 4)                 // 6250 blocks of 4 waves
#define NPB 32                               // nodes per block (node kernel)
#define NBLK ((N_NODES + NPB - 1) / NPB)     // 1563
#define NPW 8                                // nodes per wave (node kernel)
#define SCAN_B 1024
#define SCAN_NB ((N_NODES + SCAN_B - 1) / SCAN_B)   // 49

// ---------------- CSR build ----------------
__global__ __launch_bounds__(256) void hist_kernel(const int* __restrict__ ei,
                                                   int* __restrict__ count) {
    for (int e = blockIdx.x * blockDim.x + threadIdx.x; e < N_EDGES;
         e += gridDim.x * blockDim.x)
        atomicAdd(&count[ei[N_EDGES + e]], 1);
}

__global__ __launch_bounds__(SCAN_B) void scan_partial_kernel(const int* __restrict__ count,
                                                              int* __restrict__ rowptr,
                                                              int* __restrict__ blockSum) {
    __shared__ int buf[SCAN_B];
    const int b = blockIdx.x, tid = threadIdx.x;
    const int i = b * SCAN_B + tid;
    int v = (i < N_NODES) ? count[i] : 0;
    buf[tid] = v;
    __syncthreads();
    for (int off = 1; off < SCAN_B; off <<= 1) {
        int t = (tid >= off) ? buf[tid - off] : 0;
        __syncthreads();
        buf[tid] += t;
        __syncthreads();
    }
    if (i < N_NODES) rowptr[i] = buf[tid] - v;      // exclusive within block
    if (tid == SCAN_B - 1) blockSum[b] = buf[tid];
}

__global__ void scan_tops_kernel(int* __restrict__ blockSum, int* __restrict__ rowptrN) {
    const int lane = threadIdx.x;                    // 64 threads = 1 wave
    int v = (lane < SCAN_NB) ? blockSum[lane] : 0;
    int s = v;
    for (int off = 1; off < 64; off <<= 1) {
        int t = __shfl_up(s, off);
        if (lane >= off) s += t;
    }
    if (lane < SCAN_NB) blockSum[lane] = s - v;      // exclusive block offsets
    if (lane == 63) rowptrN[0] = s;
}

__global__ __launch_bounds__(SCAN_B) void scan_add_kernel(const int* __restrict__ blockSum,
                                                          int* __restrict__ rowptr,
                                                          int* __restrict__ cursor) {
    const int i = blockIdx.x * SCAN_B + threadIdx.x;
    if (i < N_NODES) {
        int r = rowptr[i] + blockSum[blockIdx.x];
        rowptr[i] = r;
        cursor[i] = r;
    }
}

// scatter edges into CSR order, copying ea rows along (no separate permute pass)
__global__ __launch_bounds__(256) void scatter_ea_kernel(const int* __restrict__ ei,
                                                         int* __restrict__ cursor,
                                                         const float4* __restrict__ ea4,
                                                         int2* __restrict__ pairsSD,
                                                         float4* __restrict__ eaP4) {
    for (int e = blockIdx.x * blockDim.x + threadIdx.x; e < N_EDGES;
         e += gridDim.x * blockDim.x) {
        int s = ei[e];
        int d = ei[N_EDGES + e];
        int pos = atomicAdd(&cursor[d], 1);
        pairsSD[pos] = make_int2(s, d);
        float4 a0 = ea4[(size_t)e * 4 + 0];
        float4 a1 = ea4[(size_t)e * 4 + 1];
        float4 a2 = ea4[(size_t)e * 4 + 2];
        float4 a3 = ea4[(size_t)e * 4 + 3];
        eaP4[(size_t)pos * 4 + 0] = a0;
        eaP4[(size_t)pos * 4 + 1] = a1;
        eaP4[(size_t)pos * 4 + 2] = a2;
        eaP4[(size_t)pos * 4 + 3] = a3;
    }
}

// ---------------- fuse readout weights ----------------
__global__ void fuse_weights_kernel(
    const float* __restrict__ W1, const float* __restrict__ b1,
    const float* __restrict__ W2, const float* __restrict__ b2,
    float* __restrict__ Wf, float* __restrict__ bf) {
    const int t = threadIdx.x;     // 128 threads
    const int i = t >> 1;
    const int j = t & 1;
    float acc = 0.f;
    for (int k = 0; k < 128; ++k) acc += W1[i * 128 + k] * W2[k * 2 + j];
    Wf[i * 2 + j] = acc;
    if (i == 0) {
        float accb = b2[j];
        for (int k = 0; k < 128; ++k) accb += b1[k] * W2[k * 2 + j];
        bf[j] = accb;
    }
}

// ---------------- edge kernel: segment-accumulate; ea prefetched 1 iter ahead ----------------
// The compute consumes ONLY values loaded >=1 iteration earlier, so the
// per-iteration s_waitcnt is a counted vmcnt (loads stay in flight across
// the iteration boundary) instead of an in-iteration full drain.
__global__ __launch_bounds__(256) void edge_kernel(
    const float* __restrict__ h,
    const int2* __restrict__ pairsSD,
    const float* __restrict__ eaP,
    const float* __restrict__ We, const float* __restrict__ be,
    float* __restrict__ aggr)
{
    const int lane = threadIdx.x & 63;
    const int gw = (blockIdx.x * 256 + threadIdx.x) >> 6;
    const int r0 = gw * EPW;
    if (r0 >= N_EDGES) return;
    const int r1 = min(r0 + EPW, N_EDGES);

    float weR[EDIM];
#pragma unroll
    for (int k = 0; k < EDIM; ++k) weR[k] = We[k * F + lane];
    const float beR = be[lane];

    // prologue: pairs depth-2, h depth-1, ea depth-1
    int2 sdA = pairsSD[r0];
    int2 sdB = pairsSD[min(r0 + 1, r1 - 1)];
    float hsA = h[((size_t)sdA.x << 6) + lane];
    const float4* ep0 = (const float4*)(eaP + ((size_t)r0 << 4));
    float4 eA0 = ep0[0], eA1 = ep0[1], eA2 = ep0[2], eA3 = ep0[3];

    int curDst = sdA.y;
    float acc = 0.f;

#pragma unroll 1
    for (int j = r0; j < r1; ++j) {
        const int jn = min(j + 1, r1 - 1);
        // issue next iteration's loads first (consumed next iteration)
        int2 sdC = pairsSD[min(j + 2, r1 - 1)];
        float hsB = h[((size_t)sdB.x << 6) + lane];
        const float4* epn = (const float4*)(eaP + ((size_t)jn << 4));
        float4 eB0 = epn[0], eB1 = epn[1], eB2 = epn[2], eB3 = epn[3];
        // compute current edge entirely from last iteration's registers
        float m = beR;
        m = fmaf(eA0.x, weR[0],  m); m = fmaf(eA0.y, weR[1],  m);
        m = fmaf(eA0.z, weR[2],  m); m = fmaf(eA0.w, weR[3],  m);
        m = fmaf(eA1.x, weR[4],  m); m = fmaf(eA1.y, weR[5],  m);
        m = fmaf(eA1.z, weR[6],  m); m = fmaf(eA1.w, weR[7],  m);
        m = fmaf(eA2.x, weR[8],  m); m = fmaf(eA2.y, weR[9],  m);
        m = fmaf(eA2.z, weR[10], m); m = fmaf(eA2.w, weR[11], m);
        m = fmaf(eA3.x, weR[12], m); m = fmaf(eA3.y, weR[13], m);
        m = fmaf(eA3.z, weR[14], m); m = fmaf(eA3.w, weR[15], m);
        if (sdA.y != curDst) {                       // wave-uniform branch
            atomicAdd(&aggr[((size_t)curDst << 6) + lane], acc);
            acc = 0.f;
            curDst = sdA.y;
        }
        acc += fmaxf(m + hsA, 0.f);                  // ReLU
        sdA = sdB; sdB = sdC; hsA = hsB;
        eA0 = eB0; eA1 = eB1; eA2 = eB2; eA3 = eB3;
    }
    atomicAdd(&aggr[((size_t)curDst << 6) + lane], acc);
}

// ---------------- node kernel: t = h + aggr; leaky(t@Wn + bn); LAST fuses readout ----------------
// Register discipline: hard cap via launch_bounds + bounded unroll window.
template <bool LAST>
__global__ __launch_bounds__(256, 4) void node_kernel(
    const float* __restrict__ h, const float* __restrict__ aggr,
    const float* __restrict__ Wn, const float* __restrict__ bn,
    const float* __restrict__ Wf, const float* __restrict__ bf,
    float* __restrict__ hout, float* __restrict__ out)
{
    __shared__ float WnS[F * F];    // 16 KB
    __shared__ float tS[NPB * F];   // 8 KB
    const int tid  = threadIdx.x;
    const int lane = tid & 63;
    const int wid  = tid >> 6;
    const int n0   = blockIdx.x * NPB;
    const int nCnt = min(NPB, N_NODES - n0);

    {   // stage Wn (coalesced float4)
        const float4* s4 = (const float4*)Wn;
        float4* d4 = (float4*)WnS;
        for (int i = tid; i < F * F / 4; i += 256) d4[i] = s4[i];
    }
    {   // stage t = h + aggr (coalesced float4), zero-pad the tail
        float4* t4 = (float4*)tS;
        const float4* h4 = (const float4*)(h + ((size_t)n0 << 6));
        const float4* a4 = (const float4*)(aggr + ((size_t)n0 << 6));
        for (int i = tid; i < NPB * F / 4; i += 256) {
            if ((i >> 4) < nCnt) {
                float4 hv = h4[i], av = a4[i];
                t4[i] = make_float4(hv.x + av.x, hv.y + av.y, hv.z + av.z, hv.w + av.w);
            } else {
                t4[i] = make_float4(0.f, 0.f, 0.f, 0.f);
            }
        }
    }
    __syncthreads();

    // wave handles 8 nodes; Wn cols + t rows both from LDS; bounded unroll
    const int nb = wid * NPW;
    const float bnR = bn[lane];
    float accv[NPW];
#pragma unroll
    for (int i = 0; i < NPW; ++i) accv[i] = bnR;
#pragma unroll 4
    for (int q = 0; q < 16; ++q) {
        const float w0 = WnS[(4 * q + 0) * F + lane];
        const float w1 = WnS[(4 * q + 1) * F + lane];
        const float w2 = WnS[(4 * q + 2) * F + lane];
        const float w3 = WnS[(4 * q + 3) * F + lane];
#pragma unroll
        for (int i = 0; i < NPW; ++i) {
            const float4 t4 = *(const float4*)&tS[((nb + i) << 6) + (q << 2)];
            accv[i] = fmaf(t4.w, w3, fmaf(t4.z, w2, fmaf(t4.y, w1, fmaf(t4.x, w0, accv[i]))));
        }
    }
    float wf0 = 0.f, wf1 = 0.f, bf0 = 0.f, bf1 = 0.f;
    if (LAST) { wf0 = Wf[lane * 2]; wf1 = Wf[lane * 2 + 1]; bf0 = bf[0]; bf1 = bf[1]; }
#pragma unroll
    for (int i = 0; i < NPW; ++i) {
        const int nl = nb + i;
        if (nl >= nCnt) break;
        float acc = accv[i];
        acc = acc >= 0.f ? acc : NEG_SLOPE * acc;    // LeakyReLU
        if (!LAST) {
            hout[((size_t)(n0 + nl) << 6) + lane] = acc;
        } else {
            float v0 = acc * wf0, v1 = acc * wf1;
#pragma unroll
            for (int off = 32; off; off >>= 1) {
                v0 += __shfl_down(v0, off);
                v1 += __shfl_down(v1, off);
            }
            if (lane == 0) {
                out[(n0 + nl) * 2 + 0] = v0 + bf0;
                out[(n0 + nl) * 2 + 1] = v1 + bf1;
            }
        }
    }
}

extern "C" void kernel_launch(void* const* d_in, const int* in_sizes, int n_in,
                              void* d_out, int out_size, void* d_ws, size_t ws_size,
                              hipStream_t stream) {
    const float* x  = (const float*)d_in[0];
    const int*   ei = (const int*)d_in[1];       // int32 per harness contract
    const float* ea = (const float*)d_in[2];
    const float* Wn = (const float*)d_in[3];
    const float* bn = (const float*)d_in[4];
    const float* We = (const float*)d_in[5];     // [3,16,64]
    const float* be = (const float*)d_in[6];     // [3,64]
    const float* W1 = (const float*)d_in[7];
    const float* b1 = (const float*)d_in[8];
    const float* W2 = (const float*)d_in[9];
    const float* b2 = (const float*)d_in[10];
    float* out = (float*)d_out;

    size_t off = 0;
    char* base = (char*)d_ws;
    auto alloc = [&](size_t bytes) {
        off = (off + 255) & ~(size_t)255;
        char* p = base + off;
        off += bytes;
        return p;
    };
    int*   count    = (int*)alloc(sizeof(int) * N_NODES);
    int*   rowptr   = (int*)alloc(sizeof(int) * (N_NODES + 1));
    int*   cursor   = (int*)alloc(sizeof(int) * N_NODES);
    int*   blockSum = (int*)alloc(sizeof(int) * SCAN_NB);
    int2*  pairsSD  = (int2*)alloc(sizeof(int2) * N_EDGES);
    float* eaP      = (float*)alloc(sizeof(float) * (size_t)N_EDGES * EDIM);
    float* aggr     = (float*)alloc(sizeof(float) * (size_t)N_NODES * F);
    float* hA       = (float*)alloc(sizeof(float) * (size_t)N_NODES * F);
    float* hB       = (float*)alloc(sizeof(float) * (size_t)N_NODES * F);
    float* Wf       = (float*)alloc(sizeof(float) * F * 2);
    float* bf       = (float*)alloc(sizeof(float) * 2);

    fuse_weights_kernel<<<1, 128, 0, stream>>>(W1, b1, W2, b2, Wf, bf);

    // CSR build (edge_index layer-invariant; ea copied into CSR order here too)
    hipMemsetAsync(count, 0, sizeof(int) * N_NODES, stream);
    hist_kernel<<<1024, 256, 0, stream>>>(ei, count);
    scan_partial_kernel<<<SCAN_NB, SCAN_B, 0, stream>>>(count, rowptr, blockSum);
    scan_tops_kernel<<<1, 64, 0, stream>>>(blockSum, rowptr + N_NODES);
    scan_add_kernel<<<SCAN_NB, SCAN_B, 0, stream>>>(blockSum, rowptr, cursor);
    scatter_ea_kernel<<<1024, 256, 0, stream>>>(ei, cursor, (const float4*)ea,
                                                pairsSD, (float4*)eaP);

    const float* hcur = x;
    float* houts[3] = {hA, hB, nullptr};
    for (int l = 0; l < 3; ++l) {
        hipMemsetAsync(aggr, 0, sizeof(float) * (size_t)N_NODES * F, stream);
        edge_kernel<<<EBLK, 256, 0, stream>>>(hcur, pairsSD, eaP,
                                              We + (size_t)l * EDIM * F,
                                              be + (size_t)l * F, aggr);
        if (l < 2) {
            node_kernel<false><<<NBLK, 256, 0, stream>>>(hcur, aggr, Wn, bn,
                                                         Wf, bf, houts[l], out);
            hcur = houts[l];
        } else {
            node_kernel<true><<<NBLK, 256, 0, stream>>>(hcur, aggr, Wn, bn,
                                                        Wf, bf, nullptr, out);
        }
    }
}

// Round 12
// 502.847 us; speedup vs baseline: 4.5555x; 1.1298x over previous
//
#include <hip/hip_runtime.h>

#define N_NODES 50000
#define N_EDGES 800000
#define F 64
#define EDIM 16
#define NEG_SLOPE 0.01f
#define G 128                                // edges per staged group (128*64B = 8KB)
#define EPB 512                              // edges per block (4 groups)
#define NBLK_E ((N_EDGES + EPB - 1) / EPB)   // 1563
#define NPB 32                               // nodes per block (node kernel)
#define NBLK ((N_NODES + NPB - 1) / NPB)     // 1563
#define NPW 8                                // nodes per wave (node kernel)
#define SCAN_B 1024
#define SCAN_NB ((N_NODES + SCAN_B - 1) / SCAN_B)   // 49

// ---------------- CSR build ----------------
__global__ __launch_bounds__(256) void hist_kernel(const int* __restrict__ ei,
                                                   int* __restrict__ count) {
    for (int e = blockIdx.x * blockDim.x + threadIdx.x; e < N_EDGES;
         e += gridDim.x * blockDim.x)
        atomicAdd(&count[ei[N_EDGES + e]], 1);
}

__global__ __launch_bounds__(SCAN_B) void scan_partial_kernel(const int* __restrict__ count,
                                                              int* __restrict__ rowptr,
                                                              int* __restrict__ blockSum) {
    __shared__ int buf[SCAN_B];
    const int b = blockIdx.x, tid = threadIdx.x;
    const int i = b * SCAN_B + tid;
    int v = (i < N_NODES) ? count[i] : 0;
    buf[tid] = v;
    __syncthreads();
    for (int off = 1; off < SCAN_B; off <<= 1) {
        int t = (tid >= off) ? buf[tid - off] : 0;
        __syncthreads();
        buf[tid] += t;
        __syncthreads();
    }
    if (i < N_NODES) rowptr[i] = buf[tid] - v;      // exclusive within block
    if (tid == SCAN_B - 1) blockSum[b] = buf[tid];
}

__global__ void scan_tops_kernel(int* __restrict__ blockSum, int* __restrict__ rowptrN) {
    const int lane = threadIdx.x;                    // 64 threads = 1 wave
    int v = (lane < SCAN_NB) ? blockSum[lane] : 0;
    int s = v;
    for (int off = 1; off < 64; off <<= 1) {
        int t = __shfl_up(s, off);
        if (lane >= off) s += t;
    }
    if (lane < SCAN_NB) blockSum[lane] = s - v;      // exclusive block offsets
    if (lane == 63) rowptrN[0] = s;
}

__global__ __launch_bounds__(SCAN_B) void scan_add_kernel(const int* __restrict__ blockSum,
                                                          int* __restrict__ rowptr,
                                                          int* __restrict__ cursor) {
    const int i = blockIdx.x * SCAN_B + threadIdx.x;
    if (i < N_NODES) {
        int r = rowptr[i] + blockSum[blockIdx.x];
        rowptr[i] = r;
        cursor[i] = r;
    }
}

// scatter edges into CSR order, copying ea rows along (no separate permute pass)
__global__ __launch_bounds__(256) void scatter_ea_kernel(const int* __restrict__ ei,
                                                         int* __restrict__ cursor,
                                                         const float4* __restrict__ ea4,
                                                         int2* __restrict__ pairsSD,
                                                         float4* __restrict__ eaP4) {
    for (int e = blockIdx.x * blockDim.x + threadIdx.x; e < N_EDGES;
         e += gridDim.x * blockDim.x) {
        int s = ei[e];
        int d = ei[N_EDGES + e];
        int pos = atomicAdd(&cursor[d], 1);
        pairsSD[pos] = make_int2(s, d);
        float4 a0 = ea4[(size_t)e * 4 + 0];
        float4 a1 = ea4[(size_t)e * 4 + 1];
        float4 a2 = ea4[(size_t)e * 4 + 2];
        float4 a3 = ea4[(size_t)e * 4 + 3];
        eaP4[(size_t)pos * 4 + 0] = a0;
        eaP4[(size_t)pos * 4 + 1] = a1;
        eaP4[(size_t)pos * 4 + 2] = a2;
        eaP4[(size_t)pos * 4 + 3] = a3;
    }
}

// ---------------- fuse readout weights ----------------
__global__ void fuse_weights_kernel(
    const float* __restrict__ W1, const float* __restrict__ b1,
    const float* __restrict__ W2, const float* __restrict__ b2,
    float* __restrict__ Wf, float* __restrict__ bf) {
    const int t = threadIdx.x;     // 128 threads
    const int i = t >> 1;
    const int j = t & 1;
    float acc = 0.f;
    for (int k = 0; k < 128; ++k) acc += W1[i * 128 + k] * W2[k * 2 + j];
    Wf[i * 2 + j] = acc;
    if (i == 0) {
        float accb = b2[j];
        for (int k = 0; k < 128; ++k) accb += b1[k] * W2[k * 2 + j];
        bf[j] = accb;
    }
}

// ---------------- edge kernel: LDS-staged ea/pairs (double-buffered) + segment-accumulate ----------------
// Block owns EPB contiguous CSR edges. ea+pairs staged per 128-edge group
// (coalesced float4 reg-stage, T14 split: loads right after barrier, ds_write
// after compute). Compute reads ea via uniform ds_read_b128 broadcasts; the
// only steady-state vmem op per edge is the h gather (depth-1 prefetched).
__global__ __launch_bounds__(256) void edge_kernel(
    const float* __restrict__ h,
    const int2* __restrict__ pairsSD,
    const float* __restrict__ eaP,
    const float* __restrict__ We, const float* __restrict__ be,
    float* __restrict__ aggr)
{
    __shared__ float eaS[2][G * EDIM];   // 2 x 8 KB
    __shared__ int2  pairsS[2][G];       // 2 x 1 KB
    const int tid  = threadIdx.x;
    const int lane = tid & 63;
    const int wid  = tid >> 6;           // 0..3

    const int eBeg = blockIdx.x * EPB;
    const int eEnd = min(eBeg + EPB, N_EDGES);
    const int ngroups = (eEnd - eBeg) / G;   // G | N_EDGES and G | EPB -> exact
    if (ngroups == 0) return;

    float weR[EDIM];
#pragma unroll
    for (int k = 0; k < EDIM; ++k) weR[k] = We[k * F + lane];
    const float beR = be[lane];

    // prologue: stage group 0 (regs -> LDS), prime per-wave sd/hs from global
    {
        const float4* gea = (const float4*)eaP + (size_t)eBeg * 4;
        float4 s0 = gea[tid], s1 = gea[tid + 256];
        int p0 = ((const int*)(pairsSD + eBeg))[tid];
        ((float4*)eaS[0])[tid] = s0;
        ((float4*)eaS[0])[tid + 256] = s1;
        ((int*)pairsS[0])[tid] = p0;
    }
    int2 sd = pairsSD[eBeg + wid * 32];
    float hs = h[((size_t)sd.x << 6) + lane];
    int curDst = sd.y;
    float acc = 0.f;

    for (int g = 0; g < ngroups; ++g) {
        const int cur = g & 1;
        __syncthreads();                 // buf[cur] visible to all waves

        // issue next group's staging loads (consumed after compute)
        float4 s0, s1;
        int p0 = 0;
        const bool hasNext = (g + 1) < ngroups;
        int2 sdF;
        float hsF = 0.f;
        if (hasNext) {
            const int nBeg = eBeg + (g + 1) * G;
            const float4* gea = (const float4*)eaP + (size_t)nBeg * 4;
            s0 = gea[tid];
            s1 = gea[tid + 256];
            p0 = ((const int*)(pairsSD + nBeg))[tid];
            sdF = pairsSD[nBeg + wid * 32];          // next group's first pair (this wave)
            hsF = h[((size_t)sdF.x << 6) + lane];    // prefetch its h row
        }

        // compute this group's 32 edges (wave-contiguous subrange)
        const float* eaC = eaS[cur];
        const int2* pC = pairsS[cur];
        const int base = wid * 32;
#pragma unroll 1
        for (int e = 0; e < 32; ++e) {
            int2 sdN = (e < 31) ? pC[base + e + 1] : (hasNext ? sdF : sd);
            float hsN = (e < 31) ? h[((size_t)sdN.x << 6) + lane] : hsF;
            const float4* ep = (const float4*)&eaC[(base + e) << 4];
            float4 q0 = ep[0], q1 = ep[1], q2 = ep[2], q3 = ep[3];
            float m = beR;
            m = fmaf(q0.x, weR[0],  m); m = fmaf(q0.y, weR[1],  m);
            m = fmaf(q0.z, weR[2],  m); m = fmaf(q0.w, weR[3],  m);
            m = fmaf(q1.x, weR[4],  m); m = fmaf(q1.y, weR[5],  m);
            m = fmaf(q1.z, weR[6],  m); m = fmaf(q1.w, weR[7],  m);
            m = fmaf(q2.x, weR[8],  m); m = fmaf(q2.y, weR[9],  m);
            m = fmaf(q2.z, weR[10], m); m = fmaf(q2.w, weR[11], m);
            m = fmaf(q3.x, weR[12], m); m = fmaf(q3.y, weR[13], m);
            m = fmaf(q3.z, weR[14], m); m = fmaf(q3.w, weR[15], m);
            if (sd.y != curDst) {                    // wave-uniform branch
                atomicAdd(&aggr[((size_t)curDst << 6) + lane], acc);
                acc = 0.f;
                curDst = sd.y;
            }
            acc += fmaxf(m + hs, 0.f);               // ReLU
            sd = sdN; hs = hsN;
        }

        // write staged regs into the other buffer (ready after next barrier)
        if (hasNext) {
            ((float4*)eaS[cur ^ 1])[tid] = s0;
            ((float4*)eaS[cur ^ 1])[tid + 256] = s1;
            ((int*)pairsS[cur ^ 1])[tid] = p0;
        }
    }
    atomicAdd(&aggr[((size_t)curDst << 6) + lane], acc);
}

// ---------------- node kernel: t = h + aggr; leaky(t@Wn + bn); LAST fuses readout ----------------
template <bool LAST>
__global__ __launch_bounds__(256, 4) void node_kernel(
    const float* __restrict__ h, const float* __restrict__ aggr,
    const float* __restrict__ Wn, const float* __restrict__ bn,
    const float* __restrict__ Wf, const float* __restrict__ bf,
    float* __restrict__ hout, float* __restrict__ out)
{
    __shared__ float WnS[F * F];    // 16 KB
    __shared__ float tS[NPB * F];   // 8 KB
    const int tid  = threadIdx.x;
    const int lane = tid & 63;
    const int wid  = tid >> 6;
    const int n0   = blockIdx.x * NPB;
    const int nCnt = min(NPB, N_NODES - n0);

    {   // stage Wn (coalesced float4)
        const float4* s4 = (const float4*)Wn;
        float4* d4 = (float4*)WnS;
        for (int i = tid; i < F * F / 4; i += 256) d4[i] = s4[i];
    }
    {   // stage t = h + aggr (coalesced float4), zero-pad the tail
        float4* t4 = (float4*)tS;
        const float4* h4 = (const float4*)(h + ((size_t)n0 << 6));
        const float4* a4 = (const float4*)(aggr + ((size_t)n0 << 6));
        for (int i = tid; i < NPB * F / 4; i += 256) {
            if ((i >> 4) < nCnt) {
                float4 hv = h4[i], av = a4[i];
                t4[i] = make_float4(hv.x + av.x, hv.y + av.y, hv.z + av.z, hv.w + av.w);
            } else {
                t4[i] = make_float4(0.f, 0.f, 0.f, 0.f);
            }
        }
    }
    __syncthreads();

    // wave handles 8 nodes; Wn cols + t rows both from LDS; bounded unroll
    const int nb = wid * NPW;
    const float bnR = bn[lane];
    float accv[NPW];
#pragma unroll
    for (int i = 0; i < NPW; ++i) accv[i] = bnR;
#pragma unroll 4
    for (int q = 0; q < 16; ++q) {
        const float w0 = WnS[(4 * q + 0) * F + lane];
        const float w1 = WnS[(4 * q + 1) * F + lane];
        const float w2 = WnS[(4 * q + 2) * F + lane];
        const float w3 = WnS[(4 * q + 3) * F + lane];
#pragma unroll
        for (int i = 0; i < NPW; ++i) {
            const float4 t4 = *(const float4*)&tS[((nb + i) << 6) + (q << 2)];
            accv[i] = fmaf(t4.w, w3, fmaf(t4.z, w2, fmaf(t4.y, w1, fmaf(t4.x, w0, accv[i]))));
        }
    }
    float wf0 = 0.f, wf1 = 0.f, bf0 = 0.f, bf1 = 0.f;
    if (LAST) { wf0 = Wf[lane * 2]; wf1 = Wf[lane * 2 + 1]; bf0 = bf[0]; bf1 = bf[1]; }
#pragma unroll
    for (int i = 0; i < NPW; ++i) {
        const int nl = nb + i;
        if (nl >= nCnt) break;
        float acc = accv[i];
        acc = acc >= 0.f ? acc : NEG_SLOPE * acc;    // LeakyReLU
        if (!LAST) {
            hout[((size_t)(n0 + nl) << 6) + lane] = acc;
        } else {
            float v0 = acc * wf0, v1 = acc * wf1;
#pragma unroll
            for (int off = 32; off; off >>= 1) {
                v0 += __shfl_down(v0, off);
                v1 += __shfl_down(v1, off);
            }
            if (lane == 0) {
                out[(n0 + nl) * 2 + 0] = v0 + bf0;
                out[(n0 + nl) * 2 + 1] = v1 + bf1;
            }
        }
    }
}

extern "C" void kernel_launch(void* const* d_in, const int* in_sizes, int n_in,
                              void* d_out, int out_size, void* d_ws, size_t ws_size,
                              hipStream_t stream) {
    const float* x  = (const float*)d_in[0];
    const int*   ei = (const int*)d_in[1];       // int32 per harness contract
    const float* ea = (const float*)d_in[2];
    const float* Wn = (const float*)d_in[3];
    const float* bn = (const float*)d_in[4];
    const float* We = (const float*)d_in[5];     // [3,16,64]
    const float* be = (const float*)d_in[6];     // [3,64]
    const float* W1 = (const float*)d_in[7];
    const float* b1 = (const float*)d_in[8];
    const float* W2 = (const float*)d_in[9];
    const float* b2 = (const float*)d_in[10];
    float* out = (float*)d_out;

    size_t off = 0;
    char* base = (char*)d_ws;
    auto alloc = [&](size_t bytes) {
        off = (off + 255) & ~(size_t)255;
        char* p = base + off;
        off += bytes;
        return p;
    };
    int*   count    = (int*)alloc(sizeof(int) * N_NODES);
    int*   rowptr   = (int*)alloc(sizeof(int) * (N_NODES + 1));
    int*   cursor   = (int*)alloc(sizeof(int) * N_NODES);
    int*   blockSum = (int*)alloc(sizeof(int) * SCAN_NB);
    int2*  pairsSD  = (int2*)alloc(sizeof(int2) * N_EDGES);
    float* eaP      = (float*)alloc(sizeof(float) * (size_t)N_EDGES * EDIM);
    float* aggr     = (float*)alloc(sizeof(float) * (size_t)N_NODES * F);
    float* hA       = (float*)alloc(sizeof(float) * (size_t)N_NODES * F);
    float* hB       = (float*)alloc(sizeof(float) * (size_t)N_NODES * F);
    float* Wf       = (float*)alloc(sizeof(float) * F * 2);
    float* bf       = (float*)alloc(sizeof(float) * 2);

    fuse_weights_kernel<<<1, 128, 0, stream>>>(W1, b1, W2, b2, Wf, bf);

    // CSR build (edge_index layer-invariant; ea copied into CSR order here too)
    hipMemsetAsync(count, 0, sizeof(int) * N_NODES, stream);
    hist_kernel<<<1024, 256, 0, stream>>>(ei, count);
    scan_partial_kernel<<<SCAN_NB, SCAN_B, 0, stream>>>(count, rowptr, blockSum);
    scan_tops_kernel<<<1, 64, 0, stream>>>(blockSum, rowptr + N_NODES);
    scan_add_kernel<<<SCAN_NB, SCAN_B, 0, stream>>>(blockSum, rowptr, cursor);
    scatter_ea_kernel<<<1024, 256, 0, stream>>>(ei, cursor, (const float4*)ea,
                                                pairsSD, (float4*)eaP);

    const float* hcur = x;
    float* houts[3] = {hA, hB, nullptr};
    for (int l = 0; l < 3; ++l) {
        hipMemsetAsync(aggr, 0, sizeof(float) * (size_t)N_NODES * F, stream);
        edge_kernel<<<NBLK_E, 256, 0, stream>>>(hcur, pairsSD, eaP,
                                                We + (size_t)l * EDIM * F,
                                                be + (size_t)l * F, aggr);
        if (l < 2) {
            node_kernel<false><<<NBLK, 256, 0, stream>>>(hcur, aggr, Wn, bn,
                                                         Wf, bf, houts[l], out);
            hcur = houts[l];
        } else {
            node_kernel<true><<<NBLK, 256, 0, stream>>>(hcur, aggr, Wn, bn,
                                                        Wf, bf, nullptr, out);
        }
    }
}

// Round 13
// 444.318 us; speedup vs baseline: 5.1556x; 1.1317x over previous
//
#include <hip/hip_runtime.h>

#define N_NODES 50000
#define N_EDGES 800000
#define F 64
#define EDIM 16
#define NEG_SLOPE 0.01f
#define G 128                                // edges per staged group (128*64B = 8KB)
#define EPB 512                              // edges per block (4 groups)
#define NBLK_E ((N_EDGES + EPB - 1) / EPB)   // 1563
#define NPB 32                               // nodes per block (node kernel)
#define NBLK ((N_NODES + NPB - 1) / NPB)     // 1563
#define NPW 8                                // nodes per wave (node kernel)
#define SCAN_B 1024
#define SCAN_NB ((N_NODES + SCAN_B - 1) / SCAN_B)   // 49

// ---------------- CSR build ----------------
__global__ __launch_bounds__(256) void hist_kernel(const int* __restrict__ ei,
                                                   int* __restrict__ count) {
    for (int e = blockIdx.x * blockDim.x + threadIdx.x; e < N_EDGES;
         e += gridDim.x * blockDim.x)
        atomicAdd(&count[ei[N_EDGES + e]], 1);
}

__global__ __launch_bounds__(SCAN_B) void scan_partial_kernel(const int* __restrict__ count,
                                                              int* __restrict__ rowptr,
                                                              int* __restrict__ blockSum) {
    __shared__ int buf[SCAN_B];
    const int b = blockIdx.x, tid = threadIdx.x;
    const int i = b * SCAN_B + tid;
    int v = (i < N_NODES) ? count[i] : 0;
    buf[tid] = v;
    __syncthreads();
    for (int off = 1; off < SCAN_B; off <<= 1) {
        int t = (tid >= off) ? buf[tid - off] : 0;
        __syncthreads();
        buf[tid] += t;
        __syncthreads();
    }
    if (i < N_NODES) rowptr[i] = buf[tid] - v;      // exclusive within block
    if (tid == SCAN_B - 1) blockSum[b] = buf[tid];
}

__global__ void scan_tops_kernel(int* __restrict__ blockSum, int* __restrict__ rowptrN) {
    const int lane = threadIdx.x;                    // 64 threads = 1 wave
    int v = (lane < SCAN_NB) ? blockSum[lane] : 0;
    int s = v;
    for (int off = 1; off < 64; off <<= 1) {
        int t = __shfl_up(s, off);
        if (lane >= off) s += t;
    }
    if (lane < SCAN_NB) blockSum[lane] = s - v;      // exclusive block offsets
    if (lane == 63) rowptrN[0] = s;
}

__global__ __launch_bounds__(SCAN_B) void scan_add_kernel(const int* __restrict__ blockSum,
                                                          int* __restrict__ rowptr,
                                                          int* __restrict__ cursor) {
    const int i = blockIdx.x * SCAN_B + threadIdx.x;
    if (i < N_NODES) {
        int r = rowptr[i] + blockSum[blockIdx.x];
        rowptr[i] = r;
        cursor[i] = r;
    }
}

// scatter edges into CSR order, copying ea rows along (no separate permute pass)
__global__ __launch_bounds__(256) void scatter_ea_kernel(const int* __restrict__ ei,
                                                         int* __restrict__ cursor,
                                                         const float4* __restrict__ ea4,
                                                         int2* __restrict__ pairsSD,
                                                         float4* __restrict__ eaP4) {
    for (int e = blockIdx.x * blockDim.x + threadIdx.x; e < N_EDGES;
         e += gridDim.x * blockDim.x) {
        int s = ei[e];
        int d = ei[N_EDGES + e];
        int pos = atomicAdd(&cursor[d], 1);
        pairsSD[pos] = make_int2(s, d);
        float4 a0 = ea4[(size_t)e * 4 + 0];
        float4 a1 = ea4[(size_t)e * 4 + 1];
        float4 a2 = ea4[(size_t)e * 4 + 2];
        float4 a3 = ea4[(size_t)e * 4 + 3];
        eaP4[(size_t)pos * 4 + 0] = a0;
        eaP4[(size_t)pos * 4 + 1] = a1;
        eaP4[(size_t)pos * 4 + 2] = a2;
        eaP4[(size_t)pos * 4 + 3] = a3;
    }
}

// ---------------- fuse readout weights ----------------
__global__ void fuse_weights_kernel(
    const float* __restrict__ W1, const float* __restrict__ b1,
    const float* __restrict__ W2, const float* __restrict__ b2,
    float* __restrict__ Wf, float* __restrict__ bf) {
    const int t = threadIdx.x;     // 128 threads
    const int i = t >> 1;
    const int j = t & 1;
    float acc = 0.f;
    for (int k = 0; k < 128; ++k) acc += W1[i * 128 + k] * W2[k * 2 + j];
    Wf[i * 2 + j] = acc;
    if (i == 0) {
        float accb = b2[j];
        for (int k = 0; k < 128; ++k) accb += b1[k] * W2[k * 2 + j];
        bf[j] = accb;
    }
}

// ---------------- edge kernel: LDS-staged ea/pairs, fully pipelined inner loop ----------------
// Invariant: nothing issued in iteration e is consumed before iteration e+1.
// pairs: 2 ahead (LDS, group-boundary values from scalar global prefetch).
// h gather: 1 ahead, address from a register that's >=1 iteration old.
// ea: 1 ahead via second ds_read_b128 register set; primed once per group.
__global__ __launch_bounds__(256) void edge_kernel(
    const float* __restrict__ h,
    const int2* __restrict__ pairsSD,
    const float* __restrict__ eaP,
    const float* __restrict__ We, const float* __restrict__ be,
    float* __restrict__ aggr)
{
    __shared__ float eaS[2][G * EDIM];   // 2 x 8 KB
    __shared__ int2  pairsS[2][G];       // 2 x 1 KB
    const int tid  = threadIdx.x;
    const int lane = tid & 63;
    const int wid  = tid >> 6;           // 0..3
    const int base = wid * 32;           // wave's subrange within a group

    const int eBeg = blockIdx.x * EPB;
    const int eEnd = min(eBeg + EPB, N_EDGES);
    const int ngroups = (eEnd - eBeg) / G;   // exact (G | EPB, G | N_EDGES)
    if (ngroups == 0) return;

    float weR[EDIM];
#pragma unroll
    for (int k = 0; k < EDIM; ++k) weR[k] = We[k * F + lane];
    const float beR = be[lane];

    // prologue: stage group 0 into LDS buffer 0; prime sdA/sdB/hsA from global
    {
        const float4* gea = (const float4*)eaP + (size_t)eBeg * 4;
        float4 s0 = gea[tid], s1 = gea[tid + 256];
        int p0 = ((const int*)(pairsSD + eBeg))[tid];
        ((float4*)eaS[0])[tid] = s0;
        ((float4*)eaS[0])[tid + 256] = s1;
        ((int*)pairsS[0])[tid] = p0;
    }
    int2 sdA = pairsSD[eBeg + base];
    int2 sdB = pairsSD[eBeg + base + 1];
    float hsA = h[((size_t)sdA.x << 6) + lane];
    int curDst = sdA.y;
    float acc = 0.f;

    for (int g = 0; g < ngroups; ++g) {
        const int cur = g & 1;
        __syncthreads();                 // buf[cur] visible to all waves

        // issue next group's staging loads + boundary pair prefetches (global)
        float4 s0, s1;
        int p0 = 0;
        const bool hasNext = (g + 1) < ngroups;
        int2 sdF0 = make_int2(0, 0), sdF1 = make_int2(0, 0);
        if (hasNext) {
            const int nBeg = eBeg + (g + 1) * G;
            const float4* gea = (const float4*)eaP + (size_t)nBeg * 4;
            s0 = gea[tid];
            s1 = gea[tid + 256];
            p0 = ((const int*)(pairsSD + nBeg))[tid];
            sdF0 = pairsSD[nBeg + base];         // wave's first 2 pairs of next group
            sdF1 = pairsSD[nBeg + base + 1];
        }

        const float* eaC = eaS[cur];
        const int2* pC = pairsS[cur];

        // prime current edge's ea (once per group; small bubble)
        const float4* ep0 = (const float4*)&eaC[(size_t)base << 4];
        float4 qA0 = ep0[0], qA1 = ep0[1], qA2 = ep0[2], qA3 = ep0[3];

#pragma unroll 1
        for (int e = 0; e < 32; ++e) {
            // pairs 2 ahead (clamped LDS read + boundary select)
            int2 ldsP = pC[min(base + e + 2, G - 1)];
            int2 sdC = (e < 30) ? ldsP : ((e == 30) ? sdF0 : sdF1);
            // h 1 ahead: sdB has been in a register since last iteration
            float hsB = h[((size_t)sdB.x << 6) + lane];
            // ea 1 ahead (clamped; e==31 value is discarded, re-primed next group)
            const float4* epn = (const float4*)&eaC[(size_t)min(base + e + 1, base + 31) << 4];
            float4 qB0 = epn[0], qB1 = epn[1], qB2 = epn[2], qB3 = epn[3];
            // compute current edge entirely from last iteration's registers
            float m = beR;
            m = fmaf(qA0.x, weR[0],  m); m = fmaf(qA0.y, weR[1],  m);
            m = fmaf(qA0.z, weR[2],  m); m = fmaf(qA0.w, weR[3],  m);
            m = fmaf(qA1.x, weR[4],  m); m = fmaf(qA1.y, weR[5],  m);
            m = fmaf(qA1.z, weR[6],  m); m = fmaf(qA1.w, weR[7],  m);
            m = fmaf(qA2.x, weR[8],  m); m = fmaf(qA2.y, weR[9],  m);
            m = fmaf(qA2.z, weR[10], m); m = fmaf(qA2.w, weR[11], m);
            m = fmaf(qA3.x, weR[12], m); m = fmaf(qA3.y, weR[13], m);
            m = fmaf(qA3.z, weR[14], m); m = fmaf(qA3.w, weR[15], m);
            if (sdA.y != curDst) {                   // wave-uniform branch
                atomicAdd(&aggr[((size_t)curDst << 6) + lane], acc);
                acc = 0.f;
                curDst = sdA.y;
            }
            acc += fmaxf(m + hsA, 0.f);              // ReLU
            sdA = sdB; sdB = sdC; hsA = hsB;
            qA0 = qB0; qA1 = qB1; qA2 = qB2; qA3 = qB3;
        }

        // write staged regs into the other buffer (ready after next barrier)
        if (hasNext) {
            ((float4*)eaS[cur ^ 1])[tid] = s0;
            ((float4*)eaS[cur ^ 1])[tid + 256] = s1;
            ((int*)pairsS[cur ^ 1])[tid] = p0;
        }
    }
    atomicAdd(&aggr[((size_t)curDst << 6) + lane], acc);
}

// ---------------- node kernel: t = h + aggr; leaky(t@Wn + bn); LAST fuses readout ----------------
template <bool LAST>
__global__ __launch_bounds__(256, 4) void node_kernel(
    const float* __restrict__ h, const float* __restrict__ aggr,
    const float* __restrict__ Wn, const float* __restrict__ bn,
    const float* __restrict__ Wf, const float* __restrict__ bf,
    float* __restrict__ hout, float* __restrict__ out)
{
    __shared__ float WnS[F * F];    // 16 KB
    __shared__ float tS[NPB * F];   // 8 KB
    const int tid  = threadIdx.x;
    const int lane = tid & 63;
    const int wid  = tid >> 6;
    const int n0   = blockIdx.x * NPB;
    const int nCnt = min(NPB, N_NODES - n0);

    {   // stage Wn (coalesced float4)
        const float4* s4 = (const float4*)Wn;
        float4* d4 = (float4*)WnS;
        for (int i = tid; i < F * F / 4; i += 256) d4[i] = s4[i];
    }
    {   // stage t = h + aggr (coalesced float4), zero-pad the tail
        float4* t4 = (float4*)tS;
        const float4* h4 = (const float4*)(h + ((size_t)n0 << 6));
        const float4* a4 = (const float4*)(aggr + ((size_t)n0 << 6));
        for (int i = tid; i < NPB * F / 4; i += 256) {
            if ((i >> 4) < nCnt) {
                float4 hv = h4[i], av = a4[i];
                t4[i] = make_float4(hv.x + av.x, hv.y + av.y, hv.z + av.z, hv.w + av.w);
            } else {
                t4[i] = make_float4(0.f, 0.f, 0.f, 0.f);
            }
        }
    }
    __syncthreads();

    // wave handles 8 nodes; Wn cols + t rows both from LDS; bounded unroll
    const int nb = wid * NPW;
    const float bnR = bn[lane];
    float accv[NPW];
#pragma unroll
    for (int i = 0; i < NPW; ++i) accv[i] = bnR;
#pragma unroll 4
    for (int q = 0; q < 16; ++q) {
        const float w0 = WnS[(4 * q + 0) * F + lane];
        const float w1 = WnS[(4 * q + 1) * F + lane];
        const float w2 = WnS[(4 * q + 2) * F + lane];
        const float w3 = WnS[(4 * q + 3) * F + lane];
#pragma unroll
        for (int i = 0; i < NPW; ++i) {
            const float4 t4 = *(const float4*)&tS[((nb + i) << 6) + (q << 2)];
            accv[i] = fmaf(t4.w, w3, fmaf(t4.z, w2, fmaf(t4.y, w1, fmaf(t4.x, w0, accv[i]))));
        }
    }
    float wf0 = 0.f, wf1 = 0.f, bf0 = 0.f, bf1 = 0.f;
    if (LAST) { wf0 = Wf[lane * 2]; wf1 = Wf[lane * 2 + 1]; bf0 = bf[0]; bf1 = bf[1]; }
#pragma unroll
    for (int i = 0; i < NPW; ++i) {
        const int nl = nb + i;
        if (nl >= nCnt) break;
        float acc = accv[i];
        acc = acc >= 0.f ? acc : NEG_SLOPE * acc;    // LeakyReLU
        if (!LAST) {
            hout[((size_t)(n0 + nl) << 6) + lane] = acc;
        } else {
            float v0 = acc * wf0, v1 = acc * wf1;
#pragma unroll
            for (int off = 32; off; off >>= 1) {
                v0 += __shfl_down(v0, off);
                v1 += __shfl_down(v1, off);
            }
            if (lane == 0) {
                out[(n0 + nl) * 2 + 0] = v0 + bf0;
                out[(n0 + nl) * 2 + 1] = v1 + bf1;
            }
        }
    }
}

extern "C" void kernel_launch(void* const* d_in, const int* in_sizes, int n_in,
                              void* d_out, int out_size, void* d_ws, size_t ws_size,
                              hipStream_t stream) {
    const float* x  = (const float*)d_in[0];
    const int*   ei = (const int*)d_in[1];       // int32 per harness contract
    const float* ea = (const float*)d_in[2];
    const float* Wn = (const float*)d_in[3];
    const float* bn = (const float*)d_in[4];
    const float* We = (const float*)d_in[5];     // [3,16,64]
    const float* be = (const float*)d_in[6];     // [3,64]
    const float* W1 = (const float*)d_in[7];
    const float* b1 = (const float*)d_in[8];
    const float* W2 = (const float*)d_in[9];
    const float* b2 = (const float*)d_in[10];
    float* out = (float*)d_out;

    size_t off = 0;
    char* base = (char*)d_ws;
    auto alloc = [&](size_t bytes) {
        off = (off + 255) & ~(size_t)255;
        char* p = base + off;
        off += bytes;
        return p;
    };
    int*   count    = (int*)alloc(sizeof(int) * N_NODES);
    int*   rowptr   = (int*)alloc(sizeof(int) * (N_NODES + 1));
    int*   cursor   = (int*)alloc(sizeof(int) * N_NODES);
    int*   blockSum = (int*)alloc(sizeof(int) * SCAN_NB);
    int2*  pairsSD  = (int2*)alloc(sizeof(int2) * N_EDGES);
    float* eaP      = (float*)alloc(sizeof(float) * (size_t)N_EDGES * EDIM);
    float* aggr     = (float*)alloc(sizeof(float) * (size_t)N_NODES * F);
    float* hA       = (float*)alloc(sizeof(float) * (size_t)N_NODES * F);
    float* hB       = (float*)alloc(sizeof(float) * (size_t)N_NODES * F);
    float* Wf       = (float*)alloc(sizeof(float) * F * 2);
    float* bf       = (float*)alloc(sizeof(float) * 2);

    fuse_weights_kernel<<<1, 128, 0, stream>>>(W1, b1, W2, b2, Wf, bf);

    // CSR build (edge_index layer-invariant; ea copied into CSR order here too)
    hipMemsetAsync(count, 0, sizeof(int) * N_NODES, stream);
    hist_kernel<<<1024, 256, 0, stream>>>(ei, count);
    scan_partial_kernel<<<SCAN_NB, SCAN_B, 0, stream>>>(count, rowptr, blockSum);
    scan_tops_kernel<<<1, 64, 0, stream>>>(blockSum, rowptr + N_NODES);
    scan_add_kernel<<<SCAN_NB, SCAN_B, 0, stream>>>(blockSum, rowptr, cursor);
    scatter_ea_kernel<<<1024, 256, 0, stream>>>(ei, cursor, (const float4*)ea,
                                                pairsSD, (float4*)eaP);

    const float* hcur = x;
    float* houts[3] = {hA, hB, nullptr};
    for (int l = 0; l < 3; ++l) {
        hipMemsetAsync(aggr, 0, sizeof(float) * (size_t)N_NODES * F, stream);
        edge_kernel<<<NBLK_E, 256, 0, stream>>>(hcur, pairsSD, eaP,
                                                We + (size_t)l * EDIM * F,
                                                be + (size_t)l * F, aggr);
        if (l < 2) {
            node_kernel<false><<<NBLK, 256, 0, stream>>>(hcur, aggr, Wn, bn,
                                                         Wf, bf, houts[l], out);
            hcur = houts[l];
        } else {
            node_kernel<true><<<NBLK, 256, 0, stream>>>(hcur, aggr, Wn, bn,
                                                        Wf, bf, nullptr, out);
        }
    }
}

// Round 14
// 365.171 us; speedup vs baseline: 6.2730x; 1.2167x over previous
//
#include <hip/hip_runtime.h>

#define N_NODES 50000
#define N_EDGES 800000
#define F 64
#define EDIM 16
#define NEG_SLOPE 0.01f
#define G 128                                // edges per staged group (128*64B = 8KB)
#define EPB 512                              // edges per block (4 groups)
#define NBLK_E ((N_EDGES + EPB - 1) / EPB)   // 1563
#define NPB 32                               // nodes per block (node kernel)
#define NBLK ((N_NODES + NPB - 1) / NPB)     // 1563
#define NPW 8                                // nodes per wave (node kernel)
#define SCAN_B 1024
#define SCAN_NB ((N_NODES + SCAN_B - 1) / SCAN_B)   // 49

// ---------------- CSR build ----------------
__global__ __launch_bounds__(256) void hist_kernel(const int* __restrict__ ei,
                                                   int* __restrict__ count) {
    for (int e = blockIdx.x * blockDim.x + threadIdx.x; e < N_EDGES;
         e += gridDim.x * blockDim.x)
        atomicAdd(&count[ei[N_EDGES + e]], 1);
}

__global__ __launch_bounds__(SCAN_B) void scan_partial_kernel(const int* __restrict__ count,
                                                              int* __restrict__ rowptr,
                                                              int* __restrict__ blockSum) {
    __shared__ int buf[SCAN_B];
    const int b = blockIdx.x, tid = threadIdx.x;
    const int i = b * SCAN_B + tid;
    int v = (i < N_NODES) ? count[i] : 0;
    buf[tid] = v;
    __syncthreads();
    for (int off = 1; off < SCAN_B; off <<= 1) {
        int t = (tid >= off) ? buf[tid - off] : 0;
        __syncthreads();
        buf[tid] += t;
        __syncthreads();
    }
    if (i < N_NODES) rowptr[i] = buf[tid] - v;      // exclusive within block
    if (tid == SCAN_B - 1) blockSum[b] = buf[tid];
}

__global__ void scan_tops_kernel(int* __restrict__ blockSum, int* __restrict__ rowptrN) {
    const int lane = threadIdx.x;                    // 64 threads = 1 wave
    int v = (lane < SCAN_NB) ? blockSum[lane] : 0;
    int s = v;
    for (int off = 1; off < 64; off <<= 1) {
        int t = __shfl_up(s, off);
        if (lane >= off) s += t;
    }
    if (lane < SCAN_NB) blockSum[lane] = s - v;      // exclusive block offsets
    if (lane == 63) rowptrN[0] = s;
}

__global__ __launch_bounds__(SCAN_B) void scan_add_kernel(const int* __restrict__ blockSum,
                                                          int* __restrict__ rowptr,
                                                          int* __restrict__ cursor) {
    const int i = blockIdx.x * SCAN_B + threadIdx.x;
    if (i < N_NODES) {
        int r = rowptr[i] + blockSum[blockIdx.x];
        rowptr[i] = r;
        cursor[i] = r;
    }
}

// scatter edges into CSR order, copying ea rows along (no separate permute pass)
__global__ __launch_bounds__(256) void scatter_ea_kernel(const int* __restrict__ ei,
                                                         int* __restrict__ cursor,
                                                         const float4* __restrict__ ea4,
                                                         int2* __restrict__ pairsSD,
                                                         float4* __restrict__ eaP4) {
    for (int e = blockIdx.x * blockDim.x + threadIdx.x; e < N_EDGES;
         e += gridDim.x * blockDim.x) {
        int s = ei[e];
        int d = ei[N_EDGES + e];
        int pos = atomicAdd(&cursor[d], 1);
        pairsSD[pos] = make_int2(s, d);
        float4 a0 = ea4[(size_t)e * 4 + 0];
        float4 a1 = ea4[(size_t)e * 4 + 1];
        float4 a2 = ea4[(size_t)e * 4 + 2];
        float4 a3 = ea4[(size_t)e * 4 + 3];
        eaP4[(size_t)pos * 4 + 0] = a0;
        eaP4[(size_t)pos * 4 + 1] = a1;
        eaP4[(size_t)pos * 4 + 2] = a2;
        eaP4[(size_t)pos * 4 + 3] = a3;
    }
}

// ---------------- fuse readout weights ----------------
__global__ void fuse_weights_kernel(
    const float* __restrict__ W1, const float* __restrict__ b1,
    const float* __restrict__ W2, const float* __restrict__ b2,
    float* __restrict__ Wf, float* __restrict__ bf) {
    const int t = threadIdx.x;     // 128 threads
    const int i = t >> 1;
    const int j = t & 1;
    float acc = 0.f;
    for (int k = 0; k < 128; ++k) acc += W1[i * 128 + k] * W2[k * 2 + j];
    Wf[i * 2 + j] = acc;
    if (i == 0) {
        float accb = b2[j];
        for (int k = 0; k < 128; ++k) accb += b1[k] * W2[k * 2 + j];
        bf[j] = accb;
    }
}

// ---------------- edge kernel: LDS-staged ea/pairs, pipelined + unroll-2 ping-pong ----------------
// Invariant: nothing issued in iteration e is consumed before iteration e+1.
// unroll 2 lets copy-propagation turn the A<-B register rotation into
// alternating names (kills ~21 v_mov per edge vs unroll 1).
__global__ __launch_bounds__(256) void edge_kernel(
    const float* __restrict__ h,
    const int2* __restrict__ pairsSD,
    const float* __restrict__ eaP,
    const float* __restrict__ We, const float* __restrict__ be,
    float* __restrict__ aggr)
{
    __shared__ float eaS[2][G * EDIM];   // 2 x 8 KB
    __shared__ int2  pairsS[2][G];       // 2 x 1 KB
    const int tid  = threadIdx.x;
    const int lane = tid & 63;
    const int wid  = tid >> 6;           // 0..3
    const int base = wid * 32;           // wave's subrange within a group

    const int eBeg = blockIdx.x * EPB;
    const int eEnd = min(eBeg + EPB, N_EDGES);
    const int ngroups = (eEnd - eBeg) / G;   // exact (G | EPB, G | N_EDGES)
    if (ngroups == 0) return;

    float weR[EDIM];
#pragma unroll
    for (int k = 0; k < EDIM; ++k) weR[k] = We[k * F + lane];
    const float beR = be[lane];

    // prologue: stage group 0 into LDS buffer 0; prime sdA/sdB/hsA from global
    {
        const float4* gea = (const float4*)eaP + (size_t)eBeg * 4;
        float4 s0 = gea[tid], s1 = gea[tid + 256];
        int p0 = ((const int*)(pairsSD + eBeg))[tid];
        ((float4*)eaS[0])[tid] = s0;
        ((float4*)eaS[0])[tid + 256] = s1;
        ((int*)pairsS[0])[tid] = p0;
    }
    int2 sdA = pairsSD[eBeg + base];
    int2 sdB = pairsSD[eBeg + base + 1];
    float hsA = h[((size_t)sdA.x << 6) + lane];
    int curDst = sdA.y;
    float acc = 0.f;

    for (int g = 0; g < ngroups; ++g) {
        const int cur = g & 1;
        __syncthreads();                 // buf[cur] visible to all waves

        // issue next group's staging loads + boundary pair prefetches (global)
        float4 s0, s1;
        int p0 = 0;
        const bool hasNext = (g + 1) < ngroups;
        int2 sdF0 = make_int2(0, 0), sdF1 = make_int2(0, 0);
        if (hasNext) {
            const int nBeg = eBeg + (g + 1) * G;
            const float4* gea = (const float4*)eaP + (size_t)nBeg * 4;
            s0 = gea[tid];
            s1 = gea[tid + 256];
            p0 = ((const int*)(pairsSD + nBeg))[tid];
            sdF0 = pairsSD[nBeg + base];         // wave's first 2 pairs of next group
            sdF1 = pairsSD[nBeg + base + 1];
        }

        const float* eaC = eaS[cur];
        const int2* pC = pairsS[cur];

        // prime current edge's ea (once per group; small bubble)
        const float4* ep0 = (const float4*)&eaC[(size_t)base << 4];
        float4 qA0 = ep0[0], qA1 = ep0[1], qA2 = ep0[2], qA3 = ep0[3];

#pragma unroll 2
        for (int e = 0; e < 32; ++e) {
            // pairs 2 ahead (clamped LDS read + boundary select)
            int2 ldsP = pC[min(base + e + 2, G - 1)];
            int2 sdC = (e < 30) ? ldsP : ((e == 30) ? sdF0 : sdF1);
            // h 1 ahead: sdB has been in a register since last iteration
            float hsB = h[((size_t)sdB.x << 6) + lane];
            // ea 1 ahead (clamped; e==31 value is discarded, re-primed next group)
            const float4* epn = (const float4*)&eaC[(size_t)min(base + e + 1, base + 31) << 4];
            float4 qB0 = epn[0], qB1 = epn[1], qB2 = epn[2], qB3 = epn[3];
            // compute current edge from last iteration's registers,
            // two independent 8-FMA partials (halves the dependent chain)
            float m0 = beR, m1 = 0.f;
            m0 = fmaf(qA0.x, weR[0],  m0); m0 = fmaf(qA0.y, weR[1],  m0);
            m0 = fmaf(qA0.z, weR[2],  m0); m0 = fmaf(qA0.w, weR[3],  m0);
            m0 = fmaf(qA1.x, weR[4],  m0); m0 = fmaf(qA1.y, weR[5],  m0);
            m0 = fmaf(qA1.z, weR[6],  m0); m0 = fmaf(qA1.w, weR[7],  m0);
            m1 = fmaf(qA2.x, weR[8],  m1); m1 = fmaf(qA2.y, weR[9],  m1);
            m1 = fmaf(qA2.z, weR[10], m1); m1 = fmaf(qA2.w, weR[11], m1);
            m1 = fmaf(qA3.x, weR[12], m1); m1 = fmaf(qA3.y, weR[13], m1);
            m1 = fmaf(qA3.z, weR[14], m1); m1 = fmaf(qA3.w, weR[15], m1);
            float m = (m0 + m1) + hsA;
            if (sdA.y != curDst) {                   // wave-uniform branch
                atomicAdd(&aggr[((size_t)curDst << 6) + lane], acc);
                acc = 0.f;
                curDst = sdA.y;
            }
            acc += fmaxf(m, 0.f);                    // ReLU
            sdA = sdB; sdB = sdC; hsA = hsB;
            qA0 = qB0; qA1 = qB1; qA2 = qB2; qA3 = qB3;
        }

        // write staged regs into the other buffer (ready after next barrier)
        if (hasNext) {
            ((float4*)eaS[cur ^ 1])[tid] = s0;
            ((float4*)eaS[cur ^ 1])[tid + 256] = s1;
            ((int*)pairsS[cur ^ 1])[tid] = p0;
        }
    }
    atomicAdd(&aggr[((size_t)curDst << 6) + lane], acc);
}

// ---------------- node kernel: t = h + aggr; leaky(t@Wn + bn); LAST fuses readout ----------------
template <bool LAST>
__global__ __launch_bounds__(256, 4) void node_kernel(
    const float* __restrict__ h, const float* __restrict__ aggr,
    const float* __restrict__ Wn, const float* __restrict__ bn,
    const float* __restrict__ Wf, const float* __restrict__ bf,
    float* __restrict__ hout, float* __restrict__ out)
{
    __shared__ float WnS[F * F];    // 16 KB
    __shared__ float tS[NPB * F];   // 8 KB
    const int tid  = threadIdx.x;
    const int lane = tid & 63;
    const int wid  = tid >> 6;
    const int n0   = blockIdx.x * NPB;
    const int nCnt = min(NPB, N_NODES - n0);

    {   // stage Wn (coalesced float4)
        const float4* s4 = (const float4*)Wn;
        float4* d4 = (float4*)WnS;
        for (int i = tid; i < F * F / 4; i += 256) d4[i] = s4[i];
    }
    {   // stage t = h + aggr (coalesced float4), zero-pad the tail
        float4* t4 = (float4*)tS;
        const float4* h4 = (const float4*)(h + ((size_t)n0 << 6));
        const float4* a4 = (const float4*)(aggr + ((size_t)n0 << 6));
        for (int i = tid; i < NPB * F / 4; i += 256) {
            if ((i >> 4) < nCnt) {
                float4 hv = h4[i], av = a4[i];
                t4[i] = make_float4(hv.x + av.x, hv.y + av.y, hv.z + av.z, hv.w + av.w);
            } else {
                t4[i] = make_float4(0.f, 0.f, 0.f, 0.f);
            }
        }
    }
    __syncthreads();

    // wave handles 8 nodes; Wn cols + t rows both from LDS; bounded unroll
    const int nb = wid * NPW;
    const float bnR = bn[lane];
    float accv[NPW];
#pragma unroll
    for (int i = 0; i < NPW; ++i) accv[i] = bnR;
#pragma unroll 4
    for (int q = 0; q < 16; ++q) {
        const float w0 = WnS[(4 * q + 0) * F + lane];
        const float w1 = WnS[(4 * q + 1) * F + lane];
        const float w2 = WnS[(4 * q + 2) * F + lane];
        const float w3 = WnS[(4 * q + 3) * F + lane];
#pragma unroll
        for (int i = 0; i < NPW; ++i) {
            const float4 t4 = *(const float4*)&tS[((nb + i) << 6) + (q << 2)];
            accv[i] = fmaf(t4.w, w3, fmaf(t4.z, w2, fmaf(t4.y, w1, fmaf(t4.x, w0, accv[i]))));
        }
    }
    float wf0 = 0.f, wf1 = 0.f, bf0 = 0.f, bf1 = 0.f;
    if (LAST) { wf0 = Wf[lane * 2]; wf1 = Wf[lane * 2 + 1]; bf0 = bf[0]; bf1 = bf[1]; }
#pragma unroll
    for (int i = 0; i < NPW; ++i) {
        const int nl = nb + i;
        if (nl >= nCnt) break;
        float acc = accv[i];
        acc = acc >= 0.f ? acc : NEG_SLOPE * acc;    // LeakyReLU
        if (!LAST) {
            hout[((size_t)(n0 + nl) << 6) + lane] = acc;
        } else {
            float v0 = acc * wf0, v1 = acc * wf1;
#pragma unroll
            for (int off = 32; off; off >>= 1) {
                v0 += __shfl_down(v0, off);
                v1 += __shfl_down(v1, off);
            }
            if (lane == 0) {
                out[(n0 + nl) * 2 + 0] = v0 + bf0;
                out[(n0 + nl) * 2 + 1] = v1 + bf1;
            }
        }
    }
}

extern "C" void kernel_launch(void* const* d_in, const int* in_sizes, int n_in,
                              void* d_out, int out_size, void* d_ws, size_t ws_size,
                              hipStream_t stream) {
    const float* x  = (const float*)d_in[0];
    const int*   ei = (const int*)d_in[1];       // int32 per harness contract
    const float* ea = (const float*)d_in[2];
    const float* Wn = (const float*)d_in[3];
    const float* bn = (const float*)d_in[4];
    const float* We = (const float*)d_in[5];     // [3,16,64]
    const float* be = (const float*)d_in[6];     // [3,64]
    const float* W1 = (const float*)d_in[7];
    const float* b1 = (const float*)d_in[8];
    const float* W2 = (const float*)d_in[9];
    const float* b2 = (const float*)d_in[10];
    float* out = (float*)d_out;

    size_t off = 0;
    char* base = (char*)d_ws;
    auto alloc = [&](size_t bytes) {
        off = (off + 255) & ~(size_t)255;
        char* p = base + off;
        off += bytes;
        return p;
    };
    int*   count    = (int*)alloc(sizeof(int) * N_NODES);
    int*   rowptr   = (int*)alloc(sizeof(int) * (N_NODES + 1));
    int*   cursor   = (int*)alloc(sizeof(int) * N_NODES);
    int*   blockSum = (int*)alloc(sizeof(int) * SCAN_NB);
    int2*  pairsSD  = (int2*)alloc(sizeof(int2) * N_EDGES);
    float* eaP      = (float*)alloc(sizeof(float) * (size_t)N_EDGES * EDIM);
    float* aggr     = (float*)alloc(sizeof(float) * (size_t)N_NODES * F);
    float* hA       = (float*)alloc(sizeof(float) * (size_t)N_NODES * F);
    float* hB       = (float*)alloc(sizeof(float) * (size_t)N_NODES * F);
    float* Wf       = (float*)alloc(sizeof(float) * F * 2);
    float* bf       = (float*)alloc(sizeof(float) * 2);

    fuse_weights_kernel<<<1, 128, 0, stream>>>(W1, b1, W2, b2, Wf, bf);

    // CSR build (edge_index layer-invariant; ea copied into CSR order here too)
    hipMemsetAsync(count, 0, sizeof(int) * N_NODES, stream);
    hist_kernel<<<1024, 256, 0, stream>>>(ei, count);
    scan_partial_kernel<<<SCAN_NB, SCAN_B, 0, stream>>>(count, rowptr, blockSum);
    scan_tops_kernel<<<1, 64, 0, stream>>>(blockSum, rowptr + N_NODES);
    scan_add_kernel<<<SCAN_NB, SCAN_B, 0, stream>>>(blockSum, rowptr, cursor);
    scatter_ea_kernel<<<1024, 256, 0, stream>>>(ei, cursor, (const float4*)ea,
                                                pairsSD, (float4*)eaP);

    const float* hcur = x;
    float* houts[3] = {hA, hB, nullptr};
    for (int l = 0; l < 3; ++l) {
        hipMemsetAsync(aggr, 0, sizeof(float) * (size_t)N_NODES * F, stream);
        edge_kernel<<<NBLK_E, 256, 0, stream>>>(hcur, pairsSD, eaP,
                                                We + (size_t)l * EDIM * F,
                                                be + (size_t)l * F, aggr);
        if (l < 2) {
            node_kernel<false><<<NBLK, 256, 0, stream>>>(hcur, aggr, Wn, bn,
                                                         Wf, bf, houts[l], out);
            hcur = houts[l];
        } else {
            node_kernel<true><<<NBLK, 256, 0, stream>>>(hcur, aggr, Wn, bn,
                                                        Wf, bf, nullptr, out);
        }
    }
}